// Round 7
// baseline (846.960 us; speedup 1.0000x reference)
//
#include <hip/hip_runtime.h>

// Multiscale Residual VQ (VAR-style), MI355X gfx950.
// Round 12: k_conv retiled 64x64 -> 128(m)x64(n), grid (64,8)=512 blocks=2/CU,
//   48KB LDS double-buffered, same global_load_lds + swizzle + 2-phase core.
//   Round-11 k_conv ran at 495 TF issued = the documented 64-row-tile ceiling;
//   128-row tiles reach ~900 TF (m97 density: ours 3.9 MFMA/KB staged vs 3.0).
//   K order (tap-major, ascending dk) and per-(m,n) MFMA triple order unchanged
//   -> bit-identical conv output. All other kernels unchanged from round 11.

#define ND 512
#define NCB 4096
#define DELTA 0.5f

typedef _Float16 half8v __attribute__((ext_vector_type(8)));
typedef float floatx4 __attribute__((ext_vector_type(4)));

struct HL { _Float16 h, l; };

__device__ __forceinline__ HL split2(float v) {
    HL r;
    r.h = (_Float16)v;
    r.l = (_Float16)((v - (float)r.h) * 4096.0f);
    return r;
}

__device__ __forceinline__ unsigned long long pack_dist(float d, int n) {
    unsigned u = __float_as_uint(d);
    u = (u & 0x80000000u) ? ~u : (u | 0x80000000u);   // monotone total order
    return ((unsigned long long)u << 32) | (unsigned)n; // tie -> lowest idx
}

__device__ __forceinline__ float unpack_dist(unsigned long long p) {
    unsigned u = (unsigned)(p >> 32);
    u = (u & 0x80000000u) ? (u & 0x7fffffffu) : ~u;
    return __uint_as_float(u);
}

// async global->LDS, 16B per lane; LDS dest = wave-uniform base + lane*16
__device__ __forceinline__ void gl2lds16(const _Float16* g, _Float16* l) {
    __builtin_amdgcn_global_load_lds(
        (const __attribute__((address_space(1))) unsigned int*)g,
        (__attribute__((address_space(3))) unsigned int*)l, 16, 0, 0);
}

// e_sq[c] = sum_d embed[c,d]^2, fp64 accumulate
__global__ __launch_bounds__(256) void k_esq(const float* __restrict__ embed,
                                             float* __restrict__ esq) {
    int c = blockIdx.x * 4 + (threadIdx.x >> 6);
    int lane = threadIdx.x & 63;
    const float* row = embed + (size_t)c * ND;
    double acc = 0.0;
#pragma unroll
    for (int i = 0; i < ND / 64; ++i) {
        float v = row[lane + i * 64];
        acc += (double)v * (double)v;
    }
#pragma unroll
    for (int off = 32; off > 0; off >>= 1) acc += __shfl_down(acc, off, 64);
    if (lane == 0) esq[c] = (float)acc;
}

// embed -> ehi/elo (4096x512 halves)
__global__ __launch_bounds__(256) void k_split_embed(const float* __restrict__ embed,
        _Float16* __restrict__ eh, _Float16* __restrict__ el) {
    int gid = blockIdx.x * 256 + threadIdx.x;       // 524288 float4s
    float4 v = ((const float4*)embed)[gid];
    HL a = split2(v.x), b = split2(v.y), c = split2(v.z), d = split2(v.w);
    _Float16* ph = eh + (size_t)gid * 4;
    _Float16* pl = el + (size_t)gid * 4;
    ph[0] = a.h; ph[1] = b.h; ph[2] = c.h; ph[3] = d.h;
    pl[0] = a.l; pl[1] = b.l; pl[2] = c.l; pl[3] = d.l;
}

// Wt2[kp][tap*512+dout][din] hi/lo from pw[kp][dout][din][tap]; output-indexed
__global__ __launch_bounds__(256) void k_split_w(const float* __restrict__ pw,
        _Float16* __restrict__ wh, _Float16* __restrict__ wl) {
    int gid = blockIdx.x * 256 + threadIdx.x;       // 4*1536*512 = 3,145,728
    int din = gid & 511;
    int nn = (gid >> 9) % 1536;
    int kp = gid / (512 * 1536);
    int tap = nn >> 9;
    int dout = nn & 511;
    float v = pw[(((size_t)(kp * 512 + dout) * 512) + din) * 3 + tap];
    HL r = split2(v);
    wh[gid] = r.h;
    wl[gid] = r.l;
}

// z[b,j,d] = block mean of src (fp64 acc) -> split halves zh/zl
__global__ __launch_bounds__(256) void k_zmean(const float* __restrict__ src,
        _Float16* __restrict__ zh, _Float16* __restrict__ zl, int s, int lg) {
    int gid = blockIdx.x * 256 + threadIdx.x;       // 16*s*512 threads
    int d = gid & 511;
    int j = (gid >> 9) & (s - 1);
    int b = gid >> (9 + lg);
    int r = 512 >> lg;
    const float* p = src + ((size_t)((b << 9) + (j << (9 - lg))) << 9) + d;
    double acc = 0.0;
#pragma unroll 4
    for (int m = 0; m < r; ++m) acc += (double)p[(size_t)m * ND];
    float v = (float)(acc * (1.0 / (double)r));
    HL hl = split2(v);
    zh[gid] = hl.h;
    zl[gid] = hl.l;
}

// ---------------- dist pass 1: hh-only GEMM, 128x128 block, 2x2 waves ----------------
// epilogue: per-(m, n-block) top-2 packed (dist,idx) -> bm2[m][32][2], no atomics
__global__ __launch_bounds__(256, 4) void k_dist1(const _Float16* __restrict__ zh,
        const _Float16* __restrict__ eh, const float* __restrict__ esq,
        unsigned long long* __restrict__ bm2, int M) {
    __shared__ _Float16 smem[2][2][4096] __attribute__((aligned(16)));  // 32 KB
    // epilogue alias (live only after the main loop's trailing barrier): 4 KB
    unsigned long long (*packs2)[2][2] =
        reinterpret_cast<unsigned long long(*)[2][2]>(&smem[0][0][0]);
    int tid = threadIdx.x;
    int lane = tid & 63, wave = tid >> 6;
    int wm = wave >> 1, wn = wave & 1;
    int quad = lane >> 4, l15 = lane & 15;
    int m0 = blockIdx.x * 128, n0 = blockIdx.y * 128;

    int slot = lane & 3;
    int r0 = wave * 32 + (lane >> 2);
    int r1 = r0 + 16;
    int sc0 = (slot ^ ((r0 >> 1) & 3)) << 3;    // swizzled source col (halves)
    int sc1 = (slot ^ ((r1 >> 1) & 3)) << 3;
    int a0 = m0 + r0; if (a0 >= M) a0 = M - 1;
    int a1 = m0 + r1; if (a1 >= M) a1 = M - 1;
    const _Float16* gA0 = zh + (size_t)a0 * 512 + sc0;
    const _Float16* gA1 = zh + (size_t)a1 * 512 + sc1;
    const _Float16* gB0 = eh + (size_t)(n0 + r0) * 512 + sc0;
    const _Float16* gB1 = eh + (size_t)(n0 + r1) * 512 + sc1;
    int ld0 = wave * 1024, ld1 = ld0 + 512;

    int cslot = (quad ^ ((l15 >> 1) & 3)) << 3;
    int rbA = (wm * 64 + l15) * 32 + cslot;
    int rbB = (wn * 64 + l15) * 32 + cslot;

#define STG(buf, kb) do { \
    gl2lds16(gA0 + (kb), &smem[buf][0][ld0]); \
    gl2lds16(gA1 + (kb), &smem[buf][0][ld1]); \
    gl2lds16(gB0 + (kb), &smem[buf][1][ld0]); \
    gl2lds16(gB1 + (kb), &smem[buf][1][ld1]); \
} while (0)

    floatx4 acc[4][4];
#pragma unroll
    for (int i = 0; i < 4; ++i)
#pragma unroll
        for (int j = 0; j < 4; ++j)
#pragma unroll
            for (int r = 0; r < 4; ++r) acc[i][j][r] = 0.f;

    STG(0, 0);
    __syncthreads();
    int cur = 0;
    for (int it = 0; it < 16; ++it) {
        if (it < 15) STG(cur ^ 1, (it + 1) * 32);
        const _Float16* sA = &smem[cur][0][0];
        const _Float16* sB = &smem[cur][1][0];
        half8v af[4], bf[4];
#pragma unroll
        for (int tm = 0; tm < 4; ++tm) af[tm] = *(const half8v*)&sA[rbA + tm * 512];
#pragma unroll
        for (int tn = 0; tn < 4; ++tn) bf[tn] = *(const half8v*)&sB[rbB + tn * 512];
#pragma unroll
        for (int tm = 0; tm < 4; ++tm)
#pragma unroll
            for (int tn = 0; tn < 4; ++tn)
                acc[tm][tn] = __builtin_amdgcn_mfma_f32_16x16x32_f16(af[tm], bf[tn], acc[tm][tn], 0, 0, 0);
        __syncthreads();
        cur ^= 1;
    }
#undef STG
    float es[4];
#pragma unroll
    for (int tn = 0; tn < 4; ++tn) es[tn] = esq[n0 + wn * 64 + tn * 16 + l15];
    // per-(m, half-block) top-2 reduction, zero atomics
#pragma unroll
    for (int tm = 0; tm < 4; ++tm)
#pragma unroll
        for (int reg = 0; reg < 4; ++reg) {
            unsigned long long b = ~0ull, sd = ~0ull;
#pragma unroll
            for (int tn = 0; tn < 4; ++tn) {
                float dd = fmaf(-2.f, acc[tm][tn][reg], es[tn]);
                int n = n0 + wn * 64 + tn * 16 + l15;
                unsigned long long p = pack_dist(dd, n);
                if (p < b) { sd = b; b = p; } else if (p < sd) sd = p;
            }
#pragma unroll
            for (int off = 1; off < 16; off <<= 1) {
                unsigned long long ob = __shfl_xor(b, off, 64);
                unsigned long long os = __shfl_xor(sd, off, 64);
                unsigned long long mx = b > ob ? b : ob;
                b = b < ob ? b : ob;
                unsigned long long mn2 = sd < os ? sd : os;
                sd = mx < mn2 ? mx : mn2;
            }
            if (l15 == 0) {
                packs2[wm * 64 + tm * 16 + quad * 4 + reg][wn][0] = b;
                packs2[wm * 64 + tm * 16 + quad * 4 + reg][wn][1] = sd;
            }
        }
    __syncthreads();
    if (tid < 128) {
        unsigned long long b0 = packs2[tid][0][0], s0 = packs2[tid][0][1];
        unsigned long long b1 = packs2[tid][1][0], s1 = packs2[tid][1][1];
        unsigned long long b = b0 < b1 ? b0 : b1;
        unsigned long long mx = b0 > b1 ? b0 : b1;
        unsigned long long mn2 = s0 < s1 ? s0 : s1;
        unsigned long long sd = mx < mn2 ? mx : mn2;
        size_t idx = ((size_t)(m0 + tid) * 32 + blockIdx.y) * 2;
        bm2[idx] = b;
        bm2[idx + 1] = sd;
    }
}

// ---------------- dist pass 2: exact refine over 64 gathered candidates ----------------
__global__ __launch_bounds__(256) void k_refine(const _Float16* __restrict__ zh,
        const _Float16* __restrict__ zl, const float* __restrict__ embed,
        const unsigned long long* __restrict__ bm2,
        unsigned long long* __restrict__ minbuf, int M) {
    int lane = threadIdx.x & 63, wave = threadIdx.x >> 6;
    int m = blockIdx.x * 4 + wave;
    if (m >= M) return;
    float zr[8];
    const _Float16* ph = zh + (size_t)m * 512 + lane * 8;
    const _Float16* pl = zl + (size_t)m * 512 + lane * 8;
#pragma unroll
    for (int i = 0; i < 8; ++i)
        zr[i] = (float)ph[i] + (float)pl[i] * (1.0f / 4096.0f);
    unsigned long long p = bm2[(size_t)m * 64 + lane];
    unsigned long long mn = p;
#pragma unroll
    for (int off = 1; off < 64; off <<= 1) {
        unsigned long long q = __shfl_xor(mn, off, 64);
        mn = q < mn ? q : mn;
    }
    float T = unpack_dist(mn) + DELTA;
    unsigned long long mask = __ballot(unpack_dist(p) <= T);
    double bestD = 1e300;
    int bestI = 0x7fffffff;
    while (mask) {
        int bit = __ffsll((unsigned long long)mask) - 1;
        mask &= mask - 1;
        int idx = (int)(unsigned)__shfl(p, bit, 64);
        const float* e = embed + (size_t)idx * 512 + lane * 8;
        double s = 0.0;
#pragma unroll
        for (int i = 0; i < 8; ++i) {
            double df = (double)zr[i] - (double)e[i];
            s += df * df;
        }
#pragma unroll
        for (int off = 32; off > 0; off >>= 1) s += __shfl_down(s, off, 64);
        if (lane == 0) {
            if (s < bestD || (s == bestD && idx < bestI)) { bestD = s; bestI = idx; }
        }
    }
    if (lane == 0) minbuf[m] = (unsigned long long)(unsigned)bestI;
}

// ---------------- phi: u[m][tap*512+dout] = (W_tap q_m)[dout], m = b*s+j ----------------
__global__ __launch_bounds__(256, 2) void k_phi(const _Float16* __restrict__ eh,
        const _Float16* __restrict__ el, const _Float16* __restrict__ wh,
        const _Float16* __restrict__ wl, const unsigned long long* __restrict__ minbuf,
        float* __restrict__ u, int M) {
    __shared__ _Float16 smem[2][4][4096] __attribute__((aligned(16)));  // 64KB exactly
    int* idxs = reinterpret_cast<int*>(&smem[0][0][0]);
    int tid = threadIdx.x;
    int lane = tid & 63, wave = tid >> 6;
    int wm = wave >> 1, wn = wave & 1;
    int quad = lane >> 4, l15 = lane & 15;
    int m0 = blockIdx.x * 128, n0 = blockIdx.y * 128;
    if (tid < 128) {
        int m = m0 + tid; if (m >= M) m = M - 1;
        idxs[tid] = (int)(unsigned)minbuf[m];
    }
    __syncthreads();

    int slot = lane & 3;
    int r0 = wave * 32 + (lane >> 2);
    int r1 = r0 + 16;
    int sc0 = (slot ^ ((r0 >> 1) & 3)) << 3;
    int sc1 = (slot ^ ((r1 >> 1) & 3)) << 3;
    int code0 = idxs[r0];
    int code1 = idxs[r1];
    __syncthreads();   // all waves done reading idxs before DMA overwrites smem
    const _Float16* gA0h = eh + (size_t)code0 * 512 + sc0;
    const _Float16* gA1h = eh + (size_t)code1 * 512 + sc1;
    const _Float16* gA0l = el + (size_t)code0 * 512 + sc0;
    const _Float16* gA1l = el + (size_t)code1 * 512 + sc1;
    const _Float16* gB0h = wh + (size_t)(n0 + r0) * 512 + sc0;
    const _Float16* gB1h = wh + (size_t)(n0 + r1) * 512 + sc1;
    const _Float16* gB0l = wl + (size_t)(n0 + r0) * 512 + sc0;
    const _Float16* gB1l = wl + (size_t)(n0 + r1) * 512 + sc1;
    int ld0 = wave * 1024;
    int ld1 = ld0 + 512;

    int cslot = (quad ^ ((l15 >> 1) & 3)) << 3;
    int rbA = (wm * 64 + l15) * 32 + cslot;
    int rbB = (wn * 64 + l15) * 32 + cslot;

#define STAGE_P(buf, kb) do { \
    gl2lds16(gA0h + (kb), &smem[buf][0][ld0]); \
    gl2lds16(gA1h + (kb), &smem[buf][0][ld1]); \
    gl2lds16(gA0l + (kb), &smem[buf][1][ld0]); \
    gl2lds16(gA1l + (kb), &smem[buf][1][ld1]); \
    gl2lds16(gB0h + (kb), &smem[buf][2][ld0]); \
    gl2lds16(gB1h + (kb), &smem[buf][2][ld1]); \
    gl2lds16(gB0l + (kb), &smem[buf][3][ld0]); \
    gl2lds16(gB1l + (kb), &smem[buf][3][ld1]); \
} while (0)

    floatx4 acch[4][4], accx[4][4];
#pragma unroll
    for (int i = 0; i < 4; ++i)
#pragma unroll
        for (int j = 0; j < 4; ++j)
#pragma unroll
            for (int r = 0; r < 4; ++r) { acch[i][j][r] = 0.f; accx[i][j][r] = 0.f; }

    STAGE_P(0, 0);
    __syncthreads();
    int cur = 0;
    for (int it = 0; it < 16; ++it) {
        if (it < 15) STAGE_P(cur ^ 1, (it + 1) * 32);
        const _Float16* sAh = &smem[cur][0][0];
        const _Float16* sAl = &smem[cur][1][0];
        const _Float16* sBh = &smem[cur][2][0];
        const _Float16* sBl = &smem[cur][3][0];
        half8v afh[4], afl[4], bfh[4], bfl[4];
#pragma unroll
        for (int tm = 0; tm < 4; ++tm) {
            afh[tm] = *(const half8v*)&sAh[rbA + tm * 512];
            afl[tm] = *(const half8v*)&sAl[rbA + tm * 512];
        }
#pragma unroll
        for (int tn = 0; tn < 4; ++tn) {
            bfh[tn] = *(const half8v*)&sBh[rbB + tn * 512];
            bfl[tn] = *(const half8v*)&sBl[rbB + tn * 512];
        }
#pragma unroll
        for (int tm = 0; tm < 4; ++tm)
#pragma unroll
            for (int tn = 0; tn < 4; ++tn) {
                acch[tm][tn] = __builtin_amdgcn_mfma_f32_16x16x32_f16(afh[tm], bfh[tn], acch[tm][tn], 0, 0, 0);
                accx[tm][tn] = __builtin_amdgcn_mfma_f32_16x16x32_f16(afh[tm], bfl[tn], accx[tm][tn], 0, 0, 0);
                accx[tm][tn] = __builtin_amdgcn_mfma_f32_16x16x32_f16(afl[tm], bfh[tn], accx[tm][tn], 0, 0, 0);
            }
        __syncthreads();
        cur ^= 1;
    }
#undef STAGE_P
#pragma unroll
    for (int tm = 0; tm < 4; ++tm)
#pragma unroll
        for (int reg = 0; reg < 4; ++reg) {
            int m = m0 + wm * 64 + tm * 16 + quad * 4 + reg;
            if (m < M) {
#pragma unroll
                for (int tn = 0; tn < 4; ++tn) {
                    int n = n0 + wn * 64 + tn * 16 + l15;
                    u[(size_t)m * 1536 + n] = acch[tm][tn][reg] + accx[tm][tn][reg] * (1.0f / 4096.0f);
                }
            }
        }
}

// combine (s<=128): resid = rsrc - (0.5*h + 0.5*(conv+bias)); h = lerp(embed[idx]),
// conv[t] = sum_tap lerp of u[.][tap] at t' = t+tap-1 ; rsrc = x at si=0
__global__ __launch_bounds__(256) void k_combine(const float* __restrict__ u,
        const float* __restrict__ embed, const unsigned long long* __restrict__ minbuf,
        const float* __restrict__ bias, const float* __restrict__ rsrc,
        float* __restrict__ resid, int s, float scale) {
    int tid = threadIdx.x;
    int m = blockIdx.x * 2 + (tid >> 7);
    int d4 = (tid & 127) << 2;
    int b = m >> 9, t = m & 511;
    int bs = b * s;
    float4 bi = *(const float4*)(bias + d4);
    float uu = ((float)t + 0.5f) * scale - 0.5f;
    float fl = floorf(uu);
    float w = uu - fl;
    int i0 = (int)fl, i1 = i0 + 1;
    i0 = min(max(i0, 0), s - 1);
    i1 = min(max(i1, 0), s - 1);
    int c0 = (int)(unsigned)minbuf[bs + i0];
    int c1 = (int)(unsigned)minbuf[bs + i1];
    float4 e0 = *(const float4*)(embed + (size_t)c0 * 512 + d4);
    float4 e1 = *(const float4*)(embed + (size_t)c1 * 512 + d4);
    float om = 1.0f - w;
    float4 h4;
    h4.x = om * e0.x + w * e1.x; h4.y = om * e0.y + w * e1.y;
    h4.z = om * e0.z + w * e1.z; h4.w = om * e0.w + w * e1.w;
    float4 conv = make_float4(0.f, 0.f, 0.f, 0.f);
#pragma unroll
    for (int tap = 0; tap < 3; ++tap) {
        int tt = t + tap - 1;
        if (tt >= 0 && tt < 512) {
            float uu2 = ((float)tt + 0.5f) * scale - 0.5f;
            float fl2 = floorf(uu2);
            float w2 = uu2 - fl2;
            int j0 = (int)fl2, j1 = j0 + 1;
            j0 = min(max(j0, 0), s - 1);
            j1 = min(max(j1, 0), s - 1);
            float4 a4 = *(const float4*)(u + (size_t)(bs + j0) * 1536 + tap * 512 + d4);
            float4 b4 = *(const float4*)(u + (size_t)(bs + j1) * 1536 + tap * 512 + d4);
            float ow = 1.0f - w2;
            conv.x += ow * a4.x + w2 * b4.x;
            conv.y += ow * a4.y + w2 * b4.y;
            conv.z += ow * a4.z + w2 * b4.z;
            conv.w += ow * a4.w + w2 * b4.w;
        }
    }
    size_t off = (size_t)m * 512 + d4;
    float4 rv = *(const float4*)(rsrc + off);
    rv.x -= 0.5f * h4.x + 0.5f * (conv.x + bi.x);
    rv.y -= 0.5f * h4.y + 0.5f * (conv.y + bi.y);
    rv.z -= 0.5f * h4.z + 0.5f * (conv.z + bi.z);
    rv.w -= 0.5f * h4.w + 0.5f * (conv.w + bi.w);
    *(float4*)(resid + off) = rv;
}

// q[b,t] = lerp(embed[c0],embed[c1],w) -> split qh/ql (8192 rows x 512)
__global__ __launch_bounds__(256) void k_prep_q(const float* __restrict__ embed,
        const unsigned long long* __restrict__ minbuf, _Float16* __restrict__ qh,
        _Float16* __restrict__ ql, int s, float scale, _Float16* __restrict__ zbuf) {
    int gid = blockIdx.x * 256 + threadIdx.x;   // 524288 threads, 8 halves each
    if (gid < 32) zbuf[gid] = (_Float16)0.f;    // 64B zero row (idempotent)
    int d8 = (gid & 63) << 3;
    int m = gid >> 6;          // b*512 + t
    int b = m >> 9, t = m & 511;
    int bs = b * s;
    float uu = ((float)t + 0.5f) * scale - 0.5f;
    float fl = floorf(uu);
    float w = uu - fl;
    int i0 = (int)fl, i1 = i0 + 1;
    i0 = min(max(i0, 0), s - 1);
    i1 = min(max(i1, 0), s - 1);
    int c0 = (int)(unsigned)minbuf[bs + i0];
    int c1 = (int)(unsigned)minbuf[bs + i1];
    const float* p0 = embed + (size_t)c0 * 512 + d8;
    const float* p1 = embed + (size_t)c1 * 512 + d8;
    float ow = 1.0f - w;
    half8v hh8, ll8;
#pragma unroll
    for (int q = 0; q < 8; ++q) {
        float v = ow * p0[q] + w * p1[q];
        HL hl = split2(v);
        hh8[q] = hl.h; ll8[q] = hl.l;
    }
    *(half8v*)(qh + (size_t)m * 512 + d8) = hh8;
    *(half8v*)(ql + (size_t)m * 512 + d8) = ll8;
}

// direct conv (s in {256,512}): GEMM [8192 x 1536(tap,din)] x [1536 x 512(dout)]
// 128(m) x 64(n) tiles, grid (64,8)=512 blocks=2/CU, 48KB LDS, 2-phase async.
// A rows = qh/ql at t' = t+tap-1 (zero row if OOB); B = Wt2 rows.
// epilogue: r2 = resid - (0.5*h + 0.5*(conv+bias)); last ? out = x - r2 : resid = r2
__global__ __launch_bounds__(256, 2) void k_conv(const _Float16* __restrict__ qh,
        const _Float16* __restrict__ ql, const float* __restrict__ embed,
        const _Float16* __restrict__ wh, const _Float16* __restrict__ wl,
        const float* __restrict__ bias, const unsigned long long* __restrict__ minbuf,
        float* __restrict__ resid, int s, float scale,
        const float* __restrict__ x, float* __restrict__ out, int last,
        const _Float16* __restrict__ zbuf) {
    // layout per buf (halves): Ah[128][32] @0, Al @4096, Bh[64][32] @8192, Bl @10240
    __shared__ _Float16 smem[2][12288] __attribute__((aligned(16))); // 48 KB
    int tid = threadIdx.x;
    int lane = tid & 63, wave = tid >> 6;
    int wm = wave >> 1, wn = wave & 1;
    int quad = lane >> 4, l15 = lane & 15;
    int m0 = blockIdx.x * 128, n0 = blockIdx.y * 64;
    int b = m0 >> 9, t0 = m0 & 511;
    // staging lane geometry: one wave call = 16 rows (64B/row)
    int rw = wave * 16 + (lane >> 2);           // A call0 / B row
    int slot = lane & 3;
    int scA0 = (slot ^ ((rw >> 1) & 3)) << 3;
    int scA1 = (slot ^ (((rw + 64) >> 1) & 3)) << 3;
    int ldw = wave * 512;                        // wave-uniform LDS base (halves)

#define STG_C(buf, itv) do { \
    int tap_ = (itv) >> 4; \
    int dk_ = ((itv) & 15) << 5; \
    int tpA0_ = t0 + rw + tap_ - 1; \
    int tpA1_ = tpA0_ + 64; \
    bool v0_ = ((unsigned)tpA0_ < 512u); \
    bool v1_ = ((unsigned)tpA1_ < 512u); \
    size_t a0_ = ((size_t)((b << 9) + (v0_ ? tpA0_ : 0)) << 9) + dk_ + scA0; \
    size_t a1_ = ((size_t)((b << 9) + (v1_ ? tpA1_ : 0)) << 9) + dk_ + scA1; \
    const _Float16* aH0_ = v0_ ? qh + a0_ : zbuf + scA0; \
    const _Float16* aL0_ = v0_ ? ql + a0_ : zbuf + scA0; \
    const _Float16* aH1_ = v1_ ? qh + a1_ : zbuf + scA1; \
    const _Float16* aL1_ = v1_ ? ql + a1_ : zbuf + scA1; \
    size_t bo_ = ((size_t)((tap_ << 9) + n0 + rw) << 9) + dk_ + scA0; \
    gl2lds16(aH0_, &smem[buf][ldw]); \
    gl2lds16(aH1_, &smem[buf][2048 + ldw]); \
    gl2lds16(aL0_, &smem[buf][4096 + ldw]); \
    gl2lds16(aL1_, &smem[buf][6144 + ldw]); \
    gl2lds16(wh + bo_, &smem[buf][8192 + ldw]); \
    gl2lds16(wl + bo_, &smem[buf][10240 + ldw]); \
} while (0)

    floatx4 acch[4][2], accx[4][2];
#pragma unroll
    for (int i = 0; i < 4; ++i)
#pragma unroll
        for (int j = 0; j < 2; ++j)
#pragma unroll
            for (int r = 0; r < 4; ++r) { acch[i][j][r] = 0.f; accx[i][j][r] = 0.f; }

    STG_C(0, 0);
    __syncthreads();
    int cur = 0;
    for (int it = 0; it < 48; ++it) {
        if (it < 47) STG_C(cur ^ 1, it + 1);
        const _Float16* sb = &smem[cur][0];
        half8v afh[4], afl[4], bfh[2], bfl[2];
#pragma unroll
        for (int tm = 0; tm < 4; ++tm) {
            int rA = wm * 64 + tm * 16 + l15;
            int cs = (quad ^ ((rA >> 1) & 3)) << 3;
            afh[tm] = *(const half8v*)&sb[rA * 32 + cs];
            afl[tm] = *(const half8v*)&sb[4096 + rA * 32 + cs];
        }
#pragma unroll
        for (int tn = 0; tn < 2; ++tn) {
            int rB = wn * 32 + tn * 16 + l15;
            int cs = (quad ^ ((rB >> 1) & 3)) << 3;
            bfh[tn] = *(const half8v*)&sb[8192 + rB * 32 + cs];
            bfl[tn] = *(const half8v*)&sb[10240 + rB * 32 + cs];
        }
#pragma unroll
        for (int tm = 0; tm < 4; ++tm)
#pragma unroll
            for (int tn = 0; tn < 2; ++tn) {
                acch[tm][tn] = __builtin_amdgcn_mfma_f32_16x16x32_f16(afh[tm], bfh[tn], acch[tm][tn], 0, 0, 0);
                accx[tm][tn] = __builtin_amdgcn_mfma_f32_16x16x32_f16(afh[tm], bfl[tn], accx[tm][tn], 0, 0, 0);
                accx[tm][tn] = __builtin_amdgcn_mfma_f32_16x16x32_f16(afl[tm], bfh[tn], accx[tm][tn], 0, 0, 0);
            }
        __syncthreads();
        cur ^= 1;
    }
#undef STG_C
#pragma unroll
    for (int tm = 0; tm < 4; ++tm)
#pragma unroll
        for (int reg = 0; reg < 4; ++reg) {
            int rrow = wm * 64 + tm * 16 + quad * 4 + reg;
            int m = m0 + rrow;
            int t = t0 + rrow;
            float uu = ((float)t + 0.5f) * scale - 0.5f;
            float fl = floorf(uu);
            float w = uu - fl;
            int i0 = (int)fl, i1 = i0 + 1;
            i0 = min(max(i0, 0), s - 1);
            i1 = min(max(i1, 0), s - 1);
            int bs = b * s;
            int c0 = (int)(unsigned)minbuf[bs + i0];
            int c1 = (int)(unsigned)minbuf[bs + i1];
            float ow = 1.0f - w;
#pragma unroll
            for (int tn = 0; tn < 2; ++tn) {
                int n = n0 + wn * 32 + tn * 16 + l15;
                float h = ow * embed[(size_t)c0 * 512 + n] + w * embed[(size_t)c1 * 512 + n];
                float val = acch[tm][tn][reg] + accx[tm][tn][reg] * (1.0f / 4096.0f);
                size_t off = (size_t)m * 512 + n;
                float r2 = resid[off] - (0.5f * h + 0.5f * (val + bias[n]));
                if (last) out[off] = x[off] - r2;
                else resid[off] = r2;
            }
        }
}

extern "C" void kernel_launch(void* const* d_in, const int* in_sizes, int n_in,
                              void* d_out, int out_size, void* d_ws, size_t ws_size,
                              hipStream_t stream) {
    const float* x     = (const float*)d_in[0];
    const float* embed = (const float*)d_in[1];
    const float* pw    = (const float*)d_in[2];
    const float* pb    = (const float*)d_in[3];
    float* out = (float*)d_out;

    // ws layout (floats), ~56.2 MB total:
    // resid 16MB | U 16MB (zh/zl = qh/ql halves; u<=12.6MB aliases after refine) |
    // ehi/elo 8MB | Wt2 hi/lo 12MB | esq 16KB | minbuf 64KB | bm2 4MB | zbuf 64B
    float* resid = (float*)d_ws;
    float* Ubase = resid + 4194304;
    _Float16* zh = (_Float16*)Ubase;            // also qh after refine (s>=256)
    _Float16* zl = zh + 4194304;                // also ql
    float* u = Ubase;
    _Float16* ehi = (_Float16*)(Ubase + 4194304);
    _Float16* elo = ehi + 2097152;
    _Float16* whi = elo + 2097152;
    _Float16* wlo = whi + 3145728;
    float* esq = (float*)(wlo + 3145728);
    unsigned long long* minbuf = (unsigned long long*)(esq + 4096);
    unsigned long long* bm2 = (unsigned long long*)(minbuf + 8192);
    _Float16* zbuf = (_Float16*)(bm2 + 524288);

    k_esq<<<1024, 256, 0, stream>>>(embed, esq);
    k_split_embed<<<2048, 256, 0, stream>>>(embed, ehi, elo);
    k_split_w<<<12288, 256, 0, stream>>>(pw, whi, wlo);

    const int SCv[10] = {1, 2, 4, 8, 16, 32, 64, 128, 256, 512};
    // PHI_IDX with float64-ulp tie-breaks at si=2 and si=7 (verified round 2)
    const int PIv[10] = {0, 0, 1, 1, 1, 2, 2, 3, 3, 3};
    for (int si = 0; si < 10; ++si) {
        int s = SCv[si];
        int M = 16 * s;
        int kp = PIv[si];
        int lg = __builtin_ctz((unsigned)s);
        float scale = (float)s / 512.0f;
        const float* src = (si == 0) ? x : resid;
        k_zmean<<<(M * 512) / 256, 256, 0, stream>>>(src, zh, zl, s, lg);
        k_dist1<<<dim3((M + 127) / 128, 32), 256, 0, stream>>>(zh, ehi, esq, bm2, M);
        k_refine<<<(M + 3) / 4, 256, 0, stream>>>(zh, zl, embed, bm2, minbuf, M);
        if (s <= 128) {
            k_phi<<<dim3((M + 127) / 128, 12), 256, 0, stream>>>(ehi, elo,
                    whi + (size_t)kp * 1536 * 512, wlo + (size_t)kp * 1536 * 512, minbuf, u, M);
            k_combine<<<4096, 256, 0, stream>>>(u, embed, minbuf, pb + kp * 512, src, resid, s, scale);
        } else {
            k_prep_q<<<2048, 256, 0, stream>>>(embed, minbuf, zh, zl, s, scale, zbuf);
            k_conv<<<dim3(64, 8), 256, 0, stream>>>(zh, zl, embed,
                    whi + (size_t)kp * 1536 * 512, wlo + (size_t)kp * 1536 * 512,
                    pb + kp * 512, minbuf, resid, s, scale, x, out, si == 9 ? 1 : 0, zbuf);
        }
    }
}

// Round 8
// 820.072 us; speedup vs baseline: 1.0328x; 1.0328x over previous
//
#include <hip/hip_runtime.h>

// Multiscale Residual VQ (VAR-style), MI355X gfx950.
// Round 13:
//   - k_conv: per-tap staging pointers hoisted out of the K-loop (18 ptrs,
//     zbuf widened to 1024 zero-halves so OOB rows absorb +dk); staging is now
//     base+dk with a uniform 3-way scalar branch. Bit-identical accumulation.
//     (Round-12 post-mortem: kernel is stall-bound at 2 blocks/CU; the only
//     cheap lever is the per-iteration conditional address VALU.)
//   - k_zmean_s for s<=8: 4-way row-split per 16-lane d-group, deterministic
//     shuffle tree; fixes 32-128-workgroup serialization (s=1 was ~17us).
//   - esq fused into k_prep_embed (split+esq in one 8MB pass, -1 launch).
// dist1/refine/phi/combine/prep_q unchanged from round 12.

#define ND 512
#define NCB 4096
#define DELTA 0.5f

typedef _Float16 half8v __attribute__((ext_vector_type(8)));
typedef float floatx4 __attribute__((ext_vector_type(4)));

struct HL { _Float16 h, l; };

__device__ __forceinline__ HL split2(float v) {
    HL r;
    r.h = (_Float16)v;
    r.l = (_Float16)((v - (float)r.h) * 4096.0f);
    return r;
}

__device__ __forceinline__ unsigned long long pack_dist(float d, int n) {
    unsigned u = __float_as_uint(d);
    u = (u & 0x80000000u) ? ~u : (u | 0x80000000u);   // monotone total order
    return ((unsigned long long)u << 32) | (unsigned)n; // tie -> lowest idx
}

__device__ __forceinline__ float unpack_dist(unsigned long long p) {
    unsigned u = (unsigned)(p >> 32);
    u = (u & 0x80000000u) ? (u & 0x7fffffffu) : ~u;
    return __uint_as_float(u);
}

// async global->LDS, 16B per lane; LDS dest = wave-uniform base + lane*16
__device__ __forceinline__ void gl2lds16(const _Float16* g, _Float16* l) {
    __builtin_amdgcn_global_load_lds(
        (const __attribute__((address_space(1))) unsigned int*)g,
        (__attribute__((address_space(3))) unsigned int*)l, 16, 0, 0);
}

// embed -> ehi/elo halves + esq (fused single pass over embed)
__global__ __launch_bounds__(256) void k_prep_embed(const float* __restrict__ embed,
        _Float16* __restrict__ eh, _Float16* __restrict__ el, float* __restrict__ esq) {
    int c = blockIdx.x * 4 + (threadIdx.x >> 6);    // 1024 blocks
    int lane = threadIdx.x & 63;
    const float* row = embed + (size_t)c * ND + lane * 8;
    float4 v0 = *(const float4*)row;
    float4 v1 = *(const float4*)(row + 4);
    float vs[8] = {v0.x, v0.y, v0.z, v0.w, v1.x, v1.y, v1.z, v1.w};
    half8v h8, l8;
    double acc = 0.0;
#pragma unroll
    for (int i = 0; i < 8; ++i) {
        HL r = split2(vs[i]);
        h8[i] = r.h; l8[i] = r.l;
        acc += (double)vs[i] * (double)vs[i];
    }
    *(half8v*)(eh + (size_t)c * ND + lane * 8) = h8;
    *(half8v*)(el + (size_t)c * ND + lane * 8) = l8;
#pragma unroll
    for (int off = 32; off > 0; off >>= 1) acc += __shfl_down(acc, off, 64);
    if (lane == 0) esq[c] = (float)acc;
}

// Wt2[kp][tap*512+dout][din] hi/lo from pw[kp][dout][din][tap]; output-indexed
__global__ __launch_bounds__(256) void k_split_w(const float* __restrict__ pw,
        _Float16* __restrict__ wh, _Float16* __restrict__ wl) {
    int gid = blockIdx.x * 256 + threadIdx.x;       // 4*1536*512 = 3,145,728
    int din = gid & 511;
    int nn = (gid >> 9) % 1536;
    int kp = gid / (512 * 1536);
    int tap = nn >> 9;
    int dout = nn & 511;
    float v = pw[(((size_t)(kp * 512 + dout) * 512) + din) * 3 + tap];
    HL r = split2(v);
    wh[gid] = r.h;
    wl[gid] = r.l;
}

// z[b,j,d] = block mean of src (fp64 acc) -> split halves zh/zl  (s >= 16)
__global__ __launch_bounds__(256) void k_zmean(const float* __restrict__ src,
        _Float16* __restrict__ zh, _Float16* __restrict__ zl, int s, int lg) {
    int gid = blockIdx.x * 256 + threadIdx.x;       // 16*s*512 threads
    int d = gid & 511;
    int j = (gid >> 9) & (s - 1);
    int b = gid >> (9 + lg);
    int r = 512 >> lg;
    const float* p = src + ((size_t)((b << 9) + (j << (9 - lg))) << 9) + d;
    double acc = 0.0;
#pragma unroll 4
    for (int m = 0; m < r; ++m) acc += (double)p[(size_t)m * ND];
    float v = (float)(acc * (1.0 / (double)r));
    HL hl = split2(v);
    zh[gid] = hl.h;
    zl[gid] = hl.l;
}

// small-s zmean (s <= 8, r = 512/s >= 64): 4-way row-split per 16-lane d-group,
// deterministic shuffle tree ((a0+a2)+(a1+a3)); 8-32x more workgroups.
__global__ __launch_bounds__(256) void k_zmean_s(const float* __restrict__ src,
        _Float16* __restrict__ zh, _Float16* __restrict__ zl, int s, int lg) {
    int bj = blockIdx.x >> 3;          // (b*s + j)
    int dblk = blockIdx.x & 7;
    int b = bj >> lg;
    int j = bj & (s - 1);
    int wave = threadIdx.x >> 6, lane = threadIdx.x & 63;
    int rg = lane >> 4;                // 0..3 row-group
    int dl = lane & 15;
    int d = dblk * 64 + wave * 16 + dl;
    int r = 512 >> lg;
    const float* p = src + ((size_t)((b << 9) + (j << (9 - lg))) << 9) + d;
    double acc = 0.0;
    for (int k = rg; k < r; k += 4) acc += (double)p[(size_t)k * ND];
    acc += __shfl_down(acc, 32, 64);   // rg0+=rg2, rg1+=rg3
    acc += __shfl_down(acc, 16, 64);   // rg0+=rg1'
    if (rg == 0) {
        float v = (float)(acc * (1.0 / (double)r));
        HL hl = split2(v);
        size_t gi = ((size_t)bj << 9) + d;
        zh[gi] = hl.h;
        zl[gi] = hl.l;
    }
}

// ---------------- dist pass 1: hh-only GEMM, 128x128 block, 2x2 waves ----------------
// epilogue: per-(m, n-block) top-2 packed (dist,idx) -> bm2[m][32][2], no atomics
__global__ __launch_bounds__(256, 4) void k_dist1(const _Float16* __restrict__ zh,
        const _Float16* __restrict__ eh, const float* __restrict__ esq,
        unsigned long long* __restrict__ bm2, int M) {
    __shared__ _Float16 smem[2][2][4096] __attribute__((aligned(16)));  // 32 KB
    // epilogue alias (live only after the main loop's trailing barrier): 4 KB
    unsigned long long (*packs2)[2][2] =
        reinterpret_cast<unsigned long long(*)[2][2]>(&smem[0][0][0]);
    int tid = threadIdx.x;
    int lane = tid & 63, wave = tid >> 6;
    int wm = wave >> 1, wn = wave & 1;
    int quad = lane >> 4, l15 = lane & 15;
    int m0 = blockIdx.x * 128, n0 = blockIdx.y * 128;

    int slot = lane & 3;
    int r0 = wave * 32 + (lane >> 2);
    int r1 = r0 + 16;
    int sc0 = (slot ^ ((r0 >> 1) & 3)) << 3;    // swizzled source col (halves)
    int sc1 = (slot ^ ((r1 >> 1) & 3)) << 3;
    int a0 = m0 + r0; if (a0 >= M) a0 = M - 1;
    int a1 = m0 + r1; if (a1 >= M) a1 = M - 1;
    const _Float16* gA0 = zh + (size_t)a0 * 512 + sc0;
    const _Float16* gA1 = zh + (size_t)a1 * 512 + sc1;
    const _Float16* gB0 = eh + (size_t)(n0 + r0) * 512 + sc0;
    const _Float16* gB1 = eh + (size_t)(n0 + r1) * 512 + sc1;
    int ld0 = wave * 1024, ld1 = ld0 + 512;

    int cslot = (quad ^ ((l15 >> 1) & 3)) << 3;
    int rbA = (wm * 64 + l15) * 32 + cslot;
    int rbB = (wn * 64 + l15) * 32 + cslot;

#define STG(buf, kb) do { \
    gl2lds16(gA0 + (kb), &smem[buf][0][ld0]); \
    gl2lds16(gA1 + (kb), &smem[buf][0][ld1]); \
    gl2lds16(gB0 + (kb), &smem[buf][1][ld0]); \
    gl2lds16(gB1 + (kb), &smem[buf][1][ld1]); \
} while (0)

    floatx4 acc[4][4];
#pragma unroll
    for (int i = 0; i < 4; ++i)
#pragma unroll
        for (int j = 0; j < 4; ++j)
#pragma unroll
            for (int r = 0; r < 4; ++r) acc[i][j][r] = 0.f;

    STG(0, 0);
    __syncthreads();
    int cur = 0;
    for (int it = 0; it < 16; ++it) {
        if (it < 15) STG(cur ^ 1, (it + 1) * 32);
        const _Float16* sA = &smem[cur][0][0];
        const _Float16* sB = &smem[cur][1][0];
        half8v af[4], bf[4];
#pragma unroll
        for (int tm = 0; tm < 4; ++tm) af[tm] = *(const half8v*)&sA[rbA + tm * 512];
#pragma unroll
        for (int tn = 0; tn < 4; ++tn) bf[tn] = *(const half8v*)&sB[rbB + tn * 512];
#pragma unroll
        for (int tm = 0; tm < 4; ++tm)
#pragma unroll
            for (int tn = 0; tn < 4; ++tn)
                acc[tm][tn] = __builtin_amdgcn_mfma_f32_16x16x32_f16(af[tm], bf[tn], acc[tm][tn], 0, 0, 0);
        __syncthreads();
        cur ^= 1;
    }
#undef STG
    float es[4];
#pragma unroll
    for (int tn = 0; tn < 4; ++tn) es[tn] = esq[n0 + wn * 64 + tn * 16 + l15];
    // per-(m, half-block) top-2 reduction, zero atomics
#pragma unroll
    for (int tm = 0; tm < 4; ++tm)
#pragma unroll
        for (int reg = 0; reg < 4; ++reg) {
            unsigned long long b = ~0ull, sd = ~0ull;
#pragma unroll
            for (int tn = 0; tn < 4; ++tn) {
                float dd = fmaf(-2.f, acc[tm][tn][reg], es[tn]);
                int n = n0 + wn * 64 + tn * 16 + l15;
                unsigned long long p = pack_dist(dd, n);
                if (p < b) { sd = b; b = p; } else if (p < sd) sd = p;
            }
#pragma unroll
            for (int off = 1; off < 16; off <<= 1) {
                unsigned long long ob = __shfl_xor(b, off, 64);
                unsigned long long os = __shfl_xor(sd, off, 64);
                unsigned long long mx = b > ob ? b : ob;
                b = b < ob ? b : ob;
                unsigned long long mn2 = sd < os ? sd : os;
                sd = mx < mn2 ? mx : mn2;
            }
            if (l15 == 0) {
                packs2[wm * 64 + tm * 16 + quad * 4 + reg][wn][0] = b;
                packs2[wm * 64 + tm * 16 + quad * 4 + reg][wn][1] = sd;
            }
        }
    __syncthreads();
    if (tid < 128) {
        unsigned long long b0 = packs2[tid][0][0], s0 = packs2[tid][0][1];
        unsigned long long b1 = packs2[tid][1][0], s1 = packs2[tid][1][1];
        unsigned long long b = b0 < b1 ? b0 : b1;
        unsigned long long mx = b0 > b1 ? b0 : b1;
        unsigned long long mn2 = s0 < s1 ? s0 : s1;
        unsigned long long sd = mx < mn2 ? mx : mn2;
        size_t idx = ((size_t)(m0 + tid) * 32 + blockIdx.y) * 2;
        bm2[idx] = b;
        bm2[idx + 1] = sd;
    }
}

// ---------------- dist pass 2: exact refine over 64 gathered candidates ----------------
__global__ __launch_bounds__(256) void k_refine(const _Float16* __restrict__ zh,
        const _Float16* __restrict__ zl, const float* __restrict__ embed,
        const unsigned long long* __restrict__ bm2,
        unsigned long long* __restrict__ minbuf, int M) {
    int lane = threadIdx.x & 63, wave = threadIdx.x >> 6;
    int m = blockIdx.x * 4 + wave;
    if (m >= M) return;
    float zr[8];
    const _Float16* ph = zh + (size_t)m * 512 + lane * 8;
    const _Float16* pl = zl + (size_t)m * 512 + lane * 8;
#pragma unroll
    for (int i = 0; i < 8; ++i)
        zr[i] = (float)ph[i] + (float)pl[i] * (1.0f / 4096.0f);
    unsigned long long p = bm2[(size_t)m * 64 + lane];
    unsigned long long mn = p;
#pragma unroll
    for (int off = 1; off < 64; off <<= 1) {
        unsigned long long q = __shfl_xor(mn, off, 64);
        mn = q < mn ? q : mn;
    }
    float T = unpack_dist(mn) + DELTA;
    unsigned long long mask = __ballot(unpack_dist(p) <= T);
    double bestD = 1e300;
    int bestI = 0x7fffffff;
    while (mask) {
        int bit = __ffsll((unsigned long long)mask) - 1;
        mask &= mask - 1;
        int idx = (int)(unsigned)__shfl(p, bit, 64);
        const float* e = embed + (size_t)idx * 512 + lane * 8;
        double s = 0.0;
#pragma unroll
        for (int i = 0; i < 8; ++i) {
            double df = (double)zr[i] - (double)e[i];
            s += df * df;
        }
#pragma unroll
        for (int off = 32; off > 0; off >>= 1) s += __shfl_down(s, off, 64);
        if (lane == 0) {
            if (s < bestD || (s == bestD && idx < bestI)) { bestD = s; bestI = idx; }
        }
    }
    if (lane == 0) minbuf[m] = (unsigned long long)(unsigned)bestI;
}

// ---------------- phi: u[m][tap*512+dout] = (W_tap q_m)[dout], m = b*s+j ----------------
__global__ __launch_bounds__(256, 2) void k_phi(const _Float16* __restrict__ eh,
        const _Float16* __restrict__ el, const _Float16* __restrict__ wh,
        const _Float16* __restrict__ wl, const unsigned long long* __restrict__ minbuf,
        float* __restrict__ u, int M) {
    __shared__ _Float16 smem[2][4][4096] __attribute__((aligned(16)));  // 64KB exactly
    int* idxs = reinterpret_cast<int*>(&smem[0][0][0]);
    int tid = threadIdx.x;
    int lane = tid & 63, wave = tid >> 6;
    int wm = wave >> 1, wn = wave & 1;
    int quad = lane >> 4, l15 = lane & 15;
    int m0 = blockIdx.x * 128, n0 = blockIdx.y * 128;
    if (tid < 128) {
        int m = m0 + tid; if (m >= M) m = M - 1;
        idxs[tid] = (int)(unsigned)minbuf[m];
    }
    __syncthreads();

    int slot = lane & 3;
    int r0 = wave * 32 + (lane >> 2);
    int r1 = r0 + 16;
    int sc0 = (slot ^ ((r0 >> 1) & 3)) << 3;
    int sc1 = (slot ^ ((r1 >> 1) & 3)) << 3;
    int code0 = idxs[r0];
    int code1 = idxs[r1];
    __syncthreads();   // all waves done reading idxs before DMA overwrites smem
    const _Float16* gA0h = eh + (size_t)code0 * 512 + sc0;
    const _Float16* gA1h = eh + (size_t)code1 * 512 + sc1;
    const _Float16* gA0l = el + (size_t)code0 * 512 + sc0;
    const _Float16* gA1l = el + (size_t)code1 * 512 + sc1;
    const _Float16* gB0h = wh + (size_t)(n0 + r0) * 512 + sc0;
    const _Float16* gB1h = wh + (size_t)(n0 + r1) * 512 + sc1;
    const _Float16* gB0l = wl + (size_t)(n0 + r0) * 512 + sc0;
    const _Float16* gB1l = wl + (size_t)(n0 + r1) * 512 + sc1;
    int ld0 = wave * 1024;
    int ld1 = ld0 + 512;

    int cslot = (quad ^ ((l15 >> 1) & 3)) << 3;
    int rbA = (wm * 64 + l15) * 32 + cslot;
    int rbB = (wn * 64 + l15) * 32 + cslot;

#define STAGE_P(buf, kb) do { \
    gl2lds16(gA0h + (kb), &smem[buf][0][ld0]); \
    gl2lds16(gA1h + (kb), &smem[buf][0][ld1]); \
    gl2lds16(gA0l + (kb), &smem[buf][1][ld0]); \
    gl2lds16(gA1l + (kb), &smem[buf][1][ld1]); \
    gl2lds16(gB0h + (kb), &smem[buf][2][ld0]); \
    gl2lds16(gB1h + (kb), &smem[buf][2][ld1]); \
    gl2lds16(gB0l + (kb), &smem[buf][3][ld0]); \
    gl2lds16(gB1l + (kb), &smem[buf][3][ld1]); \
} while (0)

    floatx4 acch[4][4], accx[4][4];
#pragma unroll
    for (int i = 0; i < 4; ++i)
#pragma unroll
        for (int j = 0; j < 4; ++j)
#pragma unroll
            for (int r = 0; r < 4; ++r) { acch[i][j][r] = 0.f; accx[i][j][r] = 0.f; }

    STAGE_P(0, 0);
    __syncthreads();
    int cur = 0;
    for (int it = 0; it < 16; ++it) {
        if (it < 15) STAGE_P(cur ^ 1, (it + 1) * 32);
        const _Float16* sAh = &smem[cur][0][0];
        const _Float16* sAl = &smem[cur][1][0];
        const _Float16* sBh = &smem[cur][2][0];
        const _Float16* sBl = &smem[cur][3][0];
        half8v afh[4], afl[4], bfh[4], bfl[4];
#pragma unroll
        for (int tm = 0; tm < 4; ++tm) {
            afh[tm] = *(const half8v*)&sAh[rbA + tm * 512];
            afl[tm] = *(const half8v*)&sAl[rbA + tm * 512];
        }
#pragma unroll
        for (int tn = 0; tn < 4; ++tn) {
            bfh[tn] = *(const half8v*)&sBh[rbB + tn * 512];
            bfl[tn] = *(const half8v*)&sBl[rbB + tn * 512];
        }
#pragma unroll
        for (int tm = 0; tm < 4; ++tm)
#pragma unroll
            for (int tn = 0; tn < 4; ++tn) {
                acch[tm][tn] = __builtin_amdgcn_mfma_f32_16x16x32_f16(afh[tm], bfh[tn], acch[tm][tn], 0, 0, 0);
                accx[tm][tn] = __builtin_amdgcn_mfma_f32_16x16x32_f16(afh[tm], bfl[tn], accx[tm][tn], 0, 0, 0);
                accx[tm][tn] = __builtin_amdgcn_mfma_f32_16x16x32_f16(afl[tm], bfh[tn], accx[tm][tn], 0, 0, 0);
            }
        __syncthreads();
        cur ^= 1;
    }
#undef STAGE_P
#pragma unroll
    for (int tm = 0; tm < 4; ++tm)
#pragma unroll
        for (int reg = 0; reg < 4; ++reg) {
            int m = m0 + wm * 64 + tm * 16 + quad * 4 + reg;
            if (m < M) {
#pragma unroll
                for (int tn = 0; tn < 4; ++tn) {
                    int n = n0 + wn * 64 + tn * 16 + l15;
                    u[(size_t)m * 1536 + n] = acch[tm][tn][reg] + accx[tm][tn][reg] * (1.0f / 4096.0f);
                }
            }
        }
}

// combine (s<=128): resid = rsrc - (0.5*h + 0.5*(conv+bias)); h = lerp(embed[idx]),
// conv[t] = sum_tap lerp of u[.][tap] at t' = t+tap-1 ; rsrc = x at si=0
__global__ __launch_bounds__(256) void k_combine(const float* __restrict__ u,
        const float* __restrict__ embed, const unsigned long long* __restrict__ minbuf,
        const float* __restrict__ bias, const float* __restrict__ rsrc,
        float* __restrict__ resid, int s, float scale) {
    int tid = threadIdx.x;
    int m = blockIdx.x * 2 + (tid >> 7);
    int d4 = (tid & 127) << 2;
    int b = m >> 9, t = m & 511;
    int bs = b * s;
    float4 bi = *(const float4*)(bias + d4);
    float uu = ((float)t + 0.5f) * scale - 0.5f;
    float fl = floorf(uu);
    float w = uu - fl;
    int i0 = (int)fl, i1 = i0 + 1;
    i0 = min(max(i0, 0), s - 1);
    i1 = min(max(i1, 0), s - 1);
    int c0 = (int)(unsigned)minbuf[bs + i0];
    int c1 = (int)(unsigned)minbuf[bs + i1];
    float4 e0 = *(const float4*)(embed + (size_t)c0 * 512 + d4);
    float4 e1 = *(const float4*)(embed + (size_t)c1 * 512 + d4);
    float om = 1.0f - w;
    float4 h4;
    h4.x = om * e0.x + w * e1.x; h4.y = om * e0.y + w * e1.y;
    h4.z = om * e0.z + w * e1.z; h4.w = om * e0.w + w * e1.w;
    float4 conv = make_float4(0.f, 0.f, 0.f, 0.f);
#pragma unroll
    for (int tap = 0; tap < 3; ++tap) {
        int tt = t + tap - 1;
        if (tt >= 0 && tt < 512) {
            float uu2 = ((float)tt + 0.5f) * scale - 0.5f;
            float fl2 = floorf(uu2);
            float w2 = uu2 - fl2;
            int j0 = (int)fl2, j1 = j0 + 1;
            j0 = min(max(j0, 0), s - 1);
            j1 = min(max(j1, 0), s - 1);
            float4 a4 = *(const float4*)(u + (size_t)(bs + j0) * 1536 + tap * 512 + d4);
            float4 b4 = *(const float4*)(u + (size_t)(bs + j1) * 1536 + tap * 512 + d4);
            float ow = 1.0f - w2;
            conv.x += ow * a4.x + w2 * b4.x;
            conv.y += ow * a4.y + w2 * b4.y;
            conv.z += ow * a4.z + w2 * b4.z;
            conv.w += ow * a4.w + w2 * b4.w;
        }
    }
    size_t off = (size_t)m * 512 + d4;
    float4 rv = *(const float4*)(rsrc + off);
    rv.x -= 0.5f * h4.x + 0.5f * (conv.x + bi.x);
    rv.y -= 0.5f * h4.y + 0.5f * (conv.y + bi.y);
    rv.z -= 0.5f * h4.z + 0.5f * (conv.z + bi.z);
    rv.w -= 0.5f * h4.w + 0.5f * (conv.w + bi.w);
    *(float4*)(resid + off) = rv;
}

// q[b,t] = lerp(embed[c0],embed[c1],w) -> split qh/ql (8192 rows x 512)
__global__ __launch_bounds__(256) void k_prep_q(const float* __restrict__ embed,
        const unsigned long long* __restrict__ minbuf, _Float16* __restrict__ qh,
        _Float16* __restrict__ ql, int s, float scale, _Float16* __restrict__ zbuf) {
    int gid = blockIdx.x * 256 + threadIdx.x;   // 524288 threads, 8 halves each
    if (gid < 1024) zbuf[gid] = (_Float16)0.f;  // 2KB zero region (full dk range)
    int d8 = (gid & 63) << 3;
    int m = gid >> 6;          // b*512 + t
    int b = m >> 9, t = m & 511;
    int bs = b * s;
    float uu = ((float)t + 0.5f) * scale - 0.5f;
    float fl = floorf(uu);
    float w = uu - fl;
    int i0 = (int)fl, i1 = i0 + 1;
    i0 = min(max(i0, 0), s - 1);
    i1 = min(max(i1, 0), s - 1);
    int c0 = (int)(unsigned)minbuf[bs + i0];
    int c1 = (int)(unsigned)minbuf[bs + i1];
    const float* p0 = embed + (size_t)c0 * 512 + d8;
    const float* p1 = embed + (size_t)c1 * 512 + d8;
    float ow = 1.0f - w;
    half8v hh8, ll8;
#pragma unroll
    for (int q = 0; q < 8; ++q) {
        float v = ow * p0[q] + w * p1[q];
        HL hl = split2(v);
        hh8[q] = hl.h; ll8[q] = hl.l;
    }
    *(half8v*)(qh + (size_t)m * 512 + d8) = hh8;
    *(half8v*)(ql + (size_t)m * 512 + d8) = ll8;
}

// direct conv (s in {256,512}): GEMM [8192 x 1536(tap,din)] x [1536 x 512(dout)]
// 128(m) x 64(n) tiles, grid (64,8)=512 blocks, 48KB LDS, 2-phase async.
// Per-tap staging pointers hoisted; zbuf(1024 zero halves) absorbs OOB rows.
// epilogue: r2 = resid - (0.5*h + 0.5*(conv+bias)); last ? out = x - r2 : resid = r2
__global__ __launch_bounds__(256, 2) void k_conv(const _Float16* __restrict__ qh,
        const _Float16* __restrict__ ql, const float* __restrict__ embed,
        const _Float16* __restrict__ wh, const _Float16* __restrict__ wl,
        const float* __restrict__ bias, const unsigned long long* __restrict__ minbuf,
        float* __restrict__ resid, int s, float scale,
        const float* __restrict__ x, float* __restrict__ out, int last,
        const _Float16* __restrict__ zbuf) {
    // layout per buf (halves): Ah[128][32] @0, Al @4096, Bh[64][32] @8192, Bl @10240
    __shared__ _Float16 smem[2][12288] __attribute__((aligned(16))); // 48 KB
    int tid = threadIdx.x;
    int lane = tid & 63, wave = tid >> 6;
    int wm = wave >> 1, wn = wave & 1;
    int quad = lane >> 4, l15 = lane & 15;
    int m0 = blockIdx.x * 128, n0 = blockIdx.y * 64;
    int b = m0 >> 9, t0 = m0 & 511;
    int rw = wave * 16 + (lane >> 2);
    int slot = lane & 3;
    int scA0 = (slot ^ ((rw >> 1) & 3)) << 3;
    int scA1 = (slot ^ (((rw + 64) >> 1) & 3)) << 3;
    int ldw = wave * 512;

    // hoisted per-tap pointers (invalid rows -> zbuf, which covers +dk range)
#define MKP(T) \
    int tp0_##T = t0 + rw + (T) - 1; \
    int tp1_##T = tp0_##T + 64; \
    const _Float16* aH0_##T = ((unsigned)tp0_##T < 512u) ? qh + (((size_t)((b << 9) + tp0_##T)) << 9) + scA0 : zbuf + scA0; \
    const _Float16* aL0_##T = ((unsigned)tp0_##T < 512u) ? ql + (((size_t)((b << 9) + tp0_##T)) << 9) + scA0 : zbuf + scA0; \
    const _Float16* aH1_##T = ((unsigned)tp1_##T < 512u) ? qh + (((size_t)((b << 9) + tp1_##T)) << 9) + scA1 : zbuf + scA1; \
    const _Float16* aL1_##T = ((unsigned)tp1_##T < 512u) ? ql + (((size_t)((b << 9) + tp1_##T)) << 9) + scA1 : zbuf + scA1; \
    const _Float16* bH_##T = wh + (((size_t)(((T) << 9) + n0 + rw)) << 9) + scA0; \
    const _Float16* bL_##T = wl + (((size_t)(((T) << 9) + n0 + rw)) << 9) + scA0;
    MKP(0)
    MKP(1)
    MKP(2)
#undef MKP

#define STG_T(buf, T, dkh) do { \
    gl2lds16(aH0_##T + (dkh), &smem[buf][ldw]); \
    gl2lds16(aH1_##T + (dkh), &smem[buf][2048 + ldw]); \
    gl2lds16(aL0_##T + (dkh), &smem[buf][4096 + ldw]); \
    gl2lds16(aL1_##T + (dkh), &smem[buf][6144 + ldw]); \
    gl2lds16(bH_##T + (dkh), &smem[buf][8192 + ldw]); \
    gl2lds16(bL_##T + (dkh), &smem[buf][10240 + ldw]); \
} while (0)

    floatx4 acch[4][2], accx[4][2];
#pragma unroll
    for (int i = 0; i < 4; ++i)
#pragma unroll
        for (int j = 0; j < 2; ++j)
#pragma unroll
            for (int r = 0; r < 4; ++r) { acch[i][j][r] = 0.f; accx[i][j][r] = 0.f; }

    STG_T(0, 0, 0);
    __syncthreads();
    int cur = 0;
    for (int it = 0; it < 48; ++it) {
        int nit = it + 1;
        int ndk = (nit & 15) << 5;
        if (nit < 16) STG_T(cur ^ 1, 0, ndk);
        else if (nit < 32) STG_T(cur ^ 1, 1, ndk);
        else if (nit < 48) STG_T(cur ^ 1, 2, ndk);
        const _Float16* sb = &smem[cur][0];
        half8v afh[4], afl[4], bfh[2], bfl[2];
#pragma unroll
        for (int tm = 0; tm < 4; ++tm) {
            int rA = wm * 64 + tm * 16 + l15;
            int cs = (quad ^ ((rA >> 1) & 3)) << 3;
            afh[tm] = *(const half8v*)&sb[rA * 32 + cs];
            afl[tm] = *(const half8v*)&sb[4096 + rA * 32 + cs];
        }
#pragma unroll
        for (int tn = 0; tn < 2; ++tn) {
            int rB = wn * 32 + tn * 16 + l15;
            int cs = (quad ^ ((rB >> 1) & 3)) << 3;
            bfh[tn] = *(const half8v*)&sb[8192 + rB * 32 + cs];
            bfl[tn] = *(const half8v*)&sb[10240 + rB * 32 + cs];
        }
#pragma unroll
        for (int tm = 0; tm < 4; ++tm)
#pragma unroll
            for (int tn = 0; tn < 2; ++tn) {
                acch[tm][tn] = __builtin_amdgcn_mfma_f32_16x16x32_f16(afh[tm], bfh[tn], acch[tm][tn], 0, 0, 0);
                accx[tm][tn] = __builtin_amdgcn_mfma_f32_16x16x32_f16(afh[tm], bfl[tn], accx[tm][tn], 0, 0, 0);
                accx[tm][tn] = __builtin_amdgcn_mfma_f32_16x16x32_f16(afl[tm], bfh[tn], accx[tm][tn], 0, 0, 0);
            }
        __syncthreads();
        cur ^= 1;
    }
#undef STG_T
#pragma unroll
    for (int tm = 0; tm < 4; ++tm)
#pragma unroll
        for (int reg = 0; reg < 4; ++reg) {
            int rrow = wm * 64 + tm * 16 + quad * 4 + reg;
            int m = m0 + rrow;
            int t = t0 + rrow;
            float uu = ((float)t + 0.5f) * scale - 0.5f;
            float fl = floorf(uu);
            float w = uu - fl;
            int i0 = (int)fl, i1 = i0 + 1;
            i0 = min(max(i0, 0), s - 1);
            i1 = min(max(i1, 0), s - 1);
            int bs = b * s;
            int c0 = (int)(unsigned)minbuf[bs + i0];
            int c1 = (int)(unsigned)minbuf[bs + i1];
            float ow = 1.0f - w;
#pragma unroll
            for (int tn = 0; tn < 2; ++tn) {
                int n = n0 + wn * 32 + tn * 16 + l15;
                float h = ow * embed[(size_t)c0 * 512 + n] + w * embed[(size_t)c1 * 512 + n];
                float val = acch[tm][tn][reg] + accx[tm][tn][reg] * (1.0f / 4096.0f);
                size_t off = (size_t)m * 512 + n;
                float r2 = resid[off] - (0.5f * h + 0.5f * (val + bias[n]));
                if (last) out[off] = x[off] - r2;
                else resid[off] = r2;
            }
        }
}

extern "C" void kernel_launch(void* const* d_in, const int* in_sizes, int n_in,
                              void* d_out, int out_size, void* d_ws, size_t ws_size,
                              hipStream_t stream) {
    const float* x     = (const float*)d_in[0];
    const float* embed = (const float*)d_in[1];
    const float* pw    = (const float*)d_in[2];
    const float* pb    = (const float*)d_in[3];
    float* out = (float*)d_out;

    // ws layout (floats), ~56.2 MB total:
    // resid 16MB | U 16MB (zh/zl = qh/ql halves; u<=12.6MB aliases after refine) |
    // ehi/elo 8MB | Wt2 hi/lo 12MB | esq 16KB | minbuf 64KB | bm2 4MB | zbuf 2KB
    float* resid = (float*)d_ws;
    float* Ubase = resid + 4194304;
    _Float16* zh = (_Float16*)Ubase;            // also qh after refine (s>=256)
    _Float16* zl = zh + 4194304;                // also ql
    float* u = Ubase;
    _Float16* ehi = (_Float16*)(Ubase + 4194304);
    _Float16* elo = ehi + 2097152;
    _Float16* whi = elo + 2097152;
    _Float16* wlo = whi + 3145728;
    float* esq = (float*)(wlo + 3145728);
    unsigned long long* minbuf = (unsigned long long*)(esq + 4096);
    unsigned long long* bm2 = (unsigned long long*)(minbuf + 8192);
    _Float16* zbuf = (_Float16*)(bm2 + 524288);

    k_prep_embed<<<1024, 256, 0, stream>>>(embed, ehi, elo, esq);
    k_split_w<<<12288, 256, 0, stream>>>(pw, whi, wlo);

    const int SCv[10] = {1, 2, 4, 8, 16, 32, 64, 128, 256, 512};
    // PHI_IDX with float64-ulp tie-breaks at si=2 and si=7 (verified round 2)
    const int PIv[10] = {0, 0, 1, 1, 1, 2, 2, 3, 3, 3};
    for (int si = 0; si < 10; ++si) {
        int s = SCv[si];
        int M = 16 * s;
        int kp = PIv[si];
        int lg = __builtin_ctz((unsigned)s);
        float scale = (float)s / 512.0f;
        const float* src = (si == 0) ? x : resid;
        if (s <= 8)
            k_zmean_s<<<16 * s * 8, 256, 0, stream>>>(src, zh, zl, s, lg);
        else
            k_zmean<<<(M * 512) / 256, 256, 0, stream>>>(src, zh, zl, s, lg);
        k_dist1<<<dim3((M + 127) / 128, 32), 256, 0, stream>>>(zh, ehi, esq, bm2, M);
        k_refine<<<(M + 3) / 4, 256, 0, stream>>>(zh, zl, embed, bm2, minbuf, M);
        if (s <= 128) {
            k_phi<<<dim3((M + 127) / 128, 12), 256, 0, stream>>>(ehi, elo,
                    whi + (size_t)kp * 1536 * 512, wlo + (size_t)kp * 1536 * 512, minbuf, u, M);
            k_combine<<<4096, 256, 0, stream>>>(u, embed, minbuf, pb + kp * 512, src, resid, s, scale);
        } else {
            k_prep_q<<<2048, 256, 0, stream>>>(embed, minbuf, zh, zl, s, scale, zbuf);
            k_conv<<<dim3(64, 8), 256, 0, stream>>>(zh, zl, embed,
                    whi + (size_t)kp * 1536 * 512, wlo + (size_t)kp * 1536 * 512,
                    pb + kp * 512, minbuf, resid, s, scale, x, out, si == 9 ? 1 : 0, zbuf);
        }
    }
}

// Round 10
// 739.965 us; speedup vs baseline: 1.1446x; 1.1083x over previous
//
#include <hip/hip_runtime.h>

// Multiscale Residual VQ (VAR-style), MI355X gfx950.
// Round 15: conv-by-linearity with DUAL-SPLIT P (round-14's single-fp16 P
// injected ~5e-4 conv error -> z perturbation ~0.01 -> argmin flips at
// near-ties -> absmax 2.875). P[c][tap*512+dout] = (W3_tap e_c) stored as
// Ph (fp16, in d_out) + Pl (fp16 residual*4096) -> reconstruction ~1e-7 rel,
// BELOW the old k_conv path's error. Pl lives in the dead Wt2 kp0-2 regions
// (whi/wlo rows 0..1535 each, dead after si=6's k_phi) + 3MB ws tail.
// k_pmat runs once at si==7 (reads only kp3 slices, disjoint from Pl writes).
// si=7/8/9 conv = k_combineP gather+lerp epilogue. s<=64 path unchanged.

#define ND 512
#define NCB 4096
#define DELTA 0.5f

typedef _Float16 half8v __attribute__((ext_vector_type(8)));
typedef _Float16 half4v __attribute__((ext_vector_type(4)));
typedef float floatx4 __attribute__((ext_vector_type(4)));

struct HL { _Float16 h, l; };

__device__ __forceinline__ HL split2(float v) {
    HL r;
    r.h = (_Float16)v;
    r.l = (_Float16)((v - (float)r.h) * 4096.0f);
    return r;
}

__device__ __forceinline__ unsigned long long pack_dist(float d, int n) {
    unsigned u = __float_as_uint(d);
    u = (u & 0x80000000u) ? ~u : (u | 0x80000000u);   // monotone total order
    return ((unsigned long long)u << 32) | (unsigned)n; // tie -> lowest idx
}

__device__ __forceinline__ float unpack_dist(unsigned long long p) {
    unsigned u = (unsigned)(p >> 32);
    u = (u & 0x80000000u) ? (u & 0x7fffffffu) : ~u;
    return __uint_as_float(u);
}

// async global->LDS, 16B per lane; LDS dest = wave-uniform base + lane*16
__device__ __forceinline__ void gl2lds16(const _Float16* g, _Float16* l) {
    __builtin_amdgcn_global_load_lds(
        (const __attribute__((address_space(1))) unsigned int*)g,
        (__attribute__((address_space(3))) unsigned int*)l, 16, 0, 0);
}

// Pl row c lives in one of three segments (whi-dead, wlo-dead, ws tail)
__device__ __forceinline__ _Float16* plrow(_Float16* p0, _Float16* p1,
                                           _Float16* p2, int c) {
    return c < 1536 ? p0 + (size_t)c * 1536
         : c < 3072 ? p1 + (size_t)(c - 1536) * 1536
                    : p2 + (size_t)(c - 3072) * 1536;
}
__device__ __forceinline__ const _Float16* plrowc(const _Float16* p0,
        const _Float16* p1, const _Float16* p2, int c) {
    return c < 1536 ? p0 + (size_t)c * 1536
         : c < 3072 ? p1 + (size_t)(c - 1536) * 1536
                    : p2 + (size_t)(c - 3072) * 1536;
}

// embed -> ehi/elo halves + esq (fused single pass over embed)
__global__ __launch_bounds__(256) void k_prep_embed(const float* __restrict__ embed,
        _Float16* __restrict__ eh, _Float16* __restrict__ el, float* __restrict__ esq) {
    int c = blockIdx.x * 4 + (threadIdx.x >> 6);    // 1024 blocks
    int lane = threadIdx.x & 63;
    const float* row = embed + (size_t)c * ND + lane * 8;
    float4 v0 = *(const float4*)row;
    float4 v1 = *(const float4*)(row + 4);
    float vs[8] = {v0.x, v0.y, v0.z, v0.w, v1.x, v1.y, v1.z, v1.w};
    half8v h8, l8;
    double acc = 0.0;
#pragma unroll
    for (int i = 0; i < 8; ++i) {
        HL r = split2(vs[i]);
        h8[i] = r.h; l8[i] = r.l;
        acc += (double)vs[i] * (double)vs[i];
    }
    *(half8v*)(eh + (size_t)c * ND + lane * 8) = h8;
    *(half8v*)(el + (size_t)c * ND + lane * 8) = l8;
#pragma unroll
    for (int off = 32; off > 0; off >>= 1) acc += __shfl_down(acc, off, 64);
    if (lane == 0) esq[c] = (float)acc;
}

// Wt2[kp][tap*512+dout][din] hi/lo from pw[kp][dout][din][tap]; output-indexed
__global__ __launch_bounds__(256) void k_split_w(const float* __restrict__ pw,
        _Float16* __restrict__ wh, _Float16* __restrict__ wl) {
    int gid = blockIdx.x * 256 + threadIdx.x;       // 4*1536*512 = 3,145,728
    int din = gid & 511;
    int nn = (gid >> 9) % 1536;
    int kp = gid / (512 * 1536);
    int tap = nn >> 9;
    int dout = nn & 511;
    float v = pw[(((size_t)(kp * 512 + dout) * 512) + din) * 3 + tap];
    HL r = split2(v);
    wh[gid] = r.h;
    wl[gid] = r.l;
}

// z[b,j,d] = block mean of src (fp64 acc) -> split halves zh/zl  (s >= 16)
__global__ __launch_bounds__(256) void k_zmean(const float* __restrict__ src,
        _Float16* __restrict__ zh, _Float16* __restrict__ zl, int s, int lg) {
    int gid = blockIdx.x * 256 + threadIdx.x;       // 16*s*512 threads
    int d = gid & 511;
    int j = (gid >> 9) & (s - 1);
    int b = gid >> (9 + lg);
    int r = 512 >> lg;
    const float* p = src + ((size_t)((b << 9) + (j << (9 - lg))) << 9) + d;
    double acc = 0.0;
#pragma unroll 4
    for (int m = 0; m < r; ++m) acc += (double)p[(size_t)m * ND];
    float v = (float)(acc * (1.0 / (double)r));
    HL hl = split2(v);
    zh[gid] = hl.h;
    zl[gid] = hl.l;
}

// small-s zmean (s <= 8, r = 512/s >= 64): 4-way row-split per 16-lane d-group,
// deterministic shuffle tree ((a0+a2)+(a1+a3)); 8-32x more workgroups.
__global__ __launch_bounds__(256) void k_zmean_s(const float* __restrict__ src,
        _Float16* __restrict__ zh, _Float16* __restrict__ zl, int s, int lg) {
    int bj = blockIdx.x >> 3;          // (b*s + j)
    int dblk = blockIdx.x & 7;
    int b = bj >> lg;
    int j = bj & (s - 1);
    int wave = threadIdx.x >> 6, lane = threadIdx.x & 63;
    int rg = lane >> 4;                // 0..3 row-group
    int dl = lane & 15;
    int d = dblk * 64 + wave * 16 + dl;
    int r = 512 >> lg;
    const float* p = src + ((size_t)((b << 9) + (j << (9 - lg))) << 9) + d;
    double acc = 0.0;
    for (int k = rg; k < r; k += 4) acc += (double)p[(size_t)k * ND];
    acc += __shfl_down(acc, 32, 64);   // rg0+=rg2, rg1+=rg3
    acc += __shfl_down(acc, 16, 64);   // rg0+=rg1'
    if (rg == 0) {
        float v = (float)(acc * (1.0 / (double)r));
        HL hl = split2(v);
        size_t gi = ((size_t)bj << 9) + d;
        zh[gi] = hl.h;
        zl[gi] = hl.l;
    }
}

// ---------------- dist pass 1: hh-only GEMM, 128x128 block, 2x2 waves ----------------
// epilogue: per-(m, n-block) top-2 packed (dist,idx) -> bm2[m][32][2], no atomics
__global__ __launch_bounds__(256, 4) void k_dist1(const _Float16* __restrict__ zh,
        const _Float16* __restrict__ eh, const float* __restrict__ esq,
        unsigned long long* __restrict__ bm2, int M) {
    __shared__ _Float16 smem[2][2][4096] __attribute__((aligned(16)));  // 32 KB
    // epilogue alias (live only after the main loop's trailing barrier): 4 KB
    unsigned long long (*packs2)[2][2] =
        reinterpret_cast<unsigned long long(*)[2][2]>(&smem[0][0][0]);
    int tid = threadIdx.x;
    int lane = tid & 63, wave = tid >> 6;
    int wm = wave >> 1, wn = wave & 1;
    int quad = lane >> 4, l15 = lane & 15;
    int m0 = blockIdx.x * 128, n0 = blockIdx.y * 128;

    int slot = lane & 3;
    int r0 = wave * 32 + (lane >> 2);
    int r1 = r0 + 16;
    int sc0 = (slot ^ ((r0 >> 1) & 3)) << 3;    // swizzled source col (halves)
    int sc1 = (slot ^ ((r1 >> 1) & 3)) << 3;
    int a0 = m0 + r0; if (a0 >= M) a0 = M - 1;
    int a1 = m0 + r1; if (a1 >= M) a1 = M - 1;
    const _Float16* gA0 = zh + (size_t)a0 * 512 + sc0;
    const _Float16* gA1 = zh + (size_t)a1 * 512 + sc1;
    const _Float16* gB0 = eh + (size_t)(n0 + r0) * 512 + sc0;
    const _Float16* gB1 = eh + (size_t)(n0 + r1) * 512 + sc1;
    int ld0 = wave * 1024, ld1 = ld0 + 512;

    int cslot = (quad ^ ((l15 >> 1) & 3)) << 3;
    int rbA = (wm * 64 + l15) * 32 + cslot;
    int rbB = (wn * 64 + l15) * 32 + cslot;

#define STG(buf, kb) do { \
    gl2lds16(gA0 + (kb), &smem[buf][0][ld0]); \
    gl2lds16(gA1 + (kb), &smem[buf][0][ld1]); \
    gl2lds16(gB0 + (kb), &smem[buf][1][ld0]); \
    gl2lds16(gB1 + (kb), &smem[buf][1][ld1]); \
} while (0)

    floatx4 acc[4][4];
#pragma unroll
    for (int i = 0; i < 4; ++i)
#pragma unroll
        for (int j = 0; j < 4; ++j)
#pragma unroll
            for (int r = 0; r < 4; ++r) acc[i][j][r] = 0.f;

    STG(0, 0);
    __syncthreads();
    int cur = 0;
    for (int it = 0; it < 16; ++it) {
        if (it < 15) STG(cur ^ 1, (it + 1) * 32);
        const _Float16* sA = &smem[cur][0][0];
        const _Float16* sB = &smem[cur][1][0];
        half8v af[4], bf[4];
#pragma unroll
        for (int tm = 0; tm < 4; ++tm) af[tm] = *(const half8v*)&sA[rbA + tm * 512];
#pragma unroll
        for (int tn = 0; tn < 4; ++tn) bf[tn] = *(const half8v*)&sB[rbB + tn * 512];
#pragma unroll
        for (int tm = 0; tm < 4; ++tm)
#pragma unroll
            for (int tn = 0; tn < 4; ++tn)
                acc[tm][tn] = __builtin_amdgcn_mfma_f32_16x16x32_f16(af[tm], bf[tn], acc[tm][tn], 0, 0, 0);
        __syncthreads();
        cur ^= 1;
    }
#undef STG
    float es[4];
#pragma unroll
    for (int tn = 0; tn < 4; ++tn) es[tn] = esq[n0 + wn * 64 + tn * 16 + l15];
    // per-(m, half-block) top-2 reduction, zero atomics
#pragma unroll
    for (int tm = 0; tm < 4; ++tm)
#pragma unroll
        for (int reg = 0; reg < 4; ++reg) {
            unsigned long long b = ~0ull, sd = ~0ull;
#pragma unroll
            for (int tn = 0; tn < 4; ++tn) {
                float dd = fmaf(-2.f, acc[tm][tn][reg], es[tn]);
                int n = n0 + wn * 64 + tn * 16 + l15;
                unsigned long long p = pack_dist(dd, n);
                if (p < b) { sd = b; b = p; } else if (p < sd) sd = p;
            }
#pragma unroll
            for (int off = 1; off < 16; off <<= 1) {
                unsigned long long ob = __shfl_xor(b, off, 64);
                unsigned long long os = __shfl_xor(sd, off, 64);
                unsigned long long mx = b > ob ? b : ob;
                b = b < ob ? b : ob;
                unsigned long long mn2 = sd < os ? sd : os;
                sd = mx < mn2 ? mx : mn2;
            }
            if (l15 == 0) {
                packs2[wm * 64 + tm * 16 + quad * 4 + reg][wn][0] = b;
                packs2[wm * 64 + tm * 16 + quad * 4 + reg][wn][1] = sd;
            }
        }
    __syncthreads();
    if (tid < 128) {
        unsigned long long b0 = packs2[tid][0][0], s0 = packs2[tid][0][1];
        unsigned long long b1 = packs2[tid][1][0], s1 = packs2[tid][1][1];
        unsigned long long b = b0 < b1 ? b0 : b1;
        unsigned long long mx = b0 > b1 ? b0 : b1;
        unsigned long long mn2 = s0 < s1 ? s0 : s1;
        unsigned long long sd = mx < mn2 ? mx : mn2;
        size_t idx = ((size_t)(m0 + tid) * 32 + blockIdx.y) * 2;
        bm2[idx] = b;
        bm2[idx + 1] = sd;
    }
}

// ---------------- dist pass 2: exact refine over 64 gathered candidates ----------------
__global__ __launch_bounds__(256) void k_refine(const _Float16* __restrict__ zh,
        const _Float16* __restrict__ zl, const float* __restrict__ embed,
        const unsigned long long* __restrict__ bm2,
        unsigned long long* __restrict__ minbuf, int M) {
    int lane = threadIdx.x & 63, wave = threadIdx.x >> 6;
    int m = blockIdx.x * 4 + wave;
    if (m >= M) return;
    float zr[8];
    const _Float16* ph = zh + (size_t)m * 512 + lane * 8;
    const _Float16* pl = zl + (size_t)m * 512 + lane * 8;
#pragma unroll
    for (int i = 0; i < 8; ++i)
        zr[i] = (float)ph[i] + (float)pl[i] * (1.0f / 4096.0f);
    unsigned long long p = bm2[(size_t)m * 64 + lane];
    unsigned long long mn = p;
#pragma unroll
    for (int off = 1; off < 64; off <<= 1) {
        unsigned long long q = __shfl_xor(mn, off, 64);
        mn = q < mn ? q : mn;
    }
    float T = unpack_dist(mn) + DELTA;
    unsigned long long mask = __ballot(unpack_dist(p) <= T);
    double bestD = 1e300;
    int bestI = 0x7fffffff;
    while (mask) {
        int bit = __ffsll((unsigned long long)mask) - 1;
        mask &= mask - 1;
        int idx = (int)(unsigned)__shfl(p, bit, 64);
        const float* e = embed + (size_t)idx * 512 + lane * 8;
        double s = 0.0;
#pragma unroll
        for (int i = 0; i < 8; ++i) {
            double df = (double)zr[i] - (double)e[i];
            s += df * df;
        }
#pragma unroll
        for (int off = 32; off > 0; off >>= 1) s += __shfl_down(s, off, 64);
        if (lane == 0) {
            if (s < bestD || (s == bestD && idx < bestI)) { bestD = s; bestI = idx; }
        }
    }
    if (lane == 0) minbuf[m] = (unsigned long long)(unsigned)bestI;
}

// ---------------- phi (s<=64): u[m][tap*512+dout] = (W_tap q_m)[dout] ----------------
__global__ __launch_bounds__(256, 2) void k_phi(const _Float16* __restrict__ eh,
        const _Float16* __restrict__ el, const _Float16* __restrict__ wh,
        const _Float16* __restrict__ wl, const unsigned long long* __restrict__ minbuf,
        float* __restrict__ u, int M) {
    __shared__ _Float16 smem[2][4][4096] __attribute__((aligned(16)));  // 64KB exactly
    int* idxs = reinterpret_cast<int*>(&smem[0][0][0]);
    int tid = threadIdx.x;
    int lane = tid & 63, wave = tid >> 6;
    int wm = wave >> 1, wn = wave & 1;
    int quad = lane >> 4, l15 = lane & 15;
    int m0 = blockIdx.x * 128, n0 = blockIdx.y * 128;
    if (tid < 128) {
        int m = m0 + tid; if (m >= M) m = M - 1;
        idxs[tid] = (int)(unsigned)minbuf[m];
    }
    __syncthreads();

    int slot = lane & 3;
    int r0 = wave * 32 + (lane >> 2);
    int r1 = r0 + 16;
    int sc0 = (slot ^ ((r0 >> 1) & 3)) << 3;
    int sc1 = (slot ^ ((r1 >> 1) & 3)) << 3;
    int code0 = idxs[r0];
    int code1 = idxs[r1];
    __syncthreads();   // all waves done reading idxs before DMA overwrites smem
    const _Float16* gA0h = eh + (size_t)code0 * 512 + sc0;
    const _Float16* gA1h = eh + (size_t)code1 * 512 + sc1;
    const _Float16* gA0l = el + (size_t)code0 * 512 + sc0;
    const _Float16* gA1l = el + (size_t)code1 * 512 + sc1;
    const _Float16* gB0h = wh + (size_t)(n0 + r0) * 512 + sc0;
    const _Float16* gB1h = wh + (size_t)(n0 + r1) * 512 + sc1;
    const _Float16* gB0l = wl + (size_t)(n0 + r0) * 512 + sc0;
    const _Float16* gB1l = wl + (size_t)(n0 + r1) * 512 + sc1;
    int ld0 = wave * 1024;
    int ld1 = ld0 + 512;

    int cslot = (quad ^ ((l15 >> 1) & 3)) << 3;
    int rbA = (wm * 64 + l15) * 32 + cslot;
    int rbB = (wn * 64 + l15) * 32 + cslot;

#define STAGE_P(buf, kb) do { \
    gl2lds16(gA0h + (kb), &smem[buf][0][ld0]); \
    gl2lds16(gA1h + (kb), &smem[buf][0][ld1]); \
    gl2lds16(gA0l + (kb), &smem[buf][1][ld0]); \
    gl2lds16(gA1l + (kb), &smem[buf][1][ld1]); \
    gl2lds16(gB0h + (kb), &smem[buf][2][ld0]); \
    gl2lds16(gB1h + (kb), &smem[buf][2][ld1]); \
    gl2lds16(gB0l + (kb), &smem[buf][3][ld0]); \
    gl2lds16(gB1l + (kb), &smem[buf][3][ld1]); \
} while (0)

    floatx4 acch[4][4], accx[4][4];
#pragma unroll
    for (int i = 0; i < 4; ++i)
#pragma unroll
        for (int j = 0; j < 4; ++j)
#pragma unroll
            for (int r = 0; r < 4; ++r) { acch[i][j][r] = 0.f; accx[i][j][r] = 0.f; }

    STAGE_P(0, 0);
    __syncthreads();
    int cur = 0;
    for (int it = 0; it < 16; ++it) {
        if (it < 15) STAGE_P(cur ^ 1, (it + 1) * 32);
        const _Float16* sAh = &smem[cur][0][0];
        const _Float16* sAl = &smem[cur][1][0];
        const _Float16* sBh = &smem[cur][2][0];
        const _Float16* sBl = &smem[cur][3][0];
        half8v afh[4], afl[4], bfh[4], bfl[4];
#pragma unroll
        for (int tm = 0; tm < 4; ++tm) {
            afh[tm] = *(const half8v*)&sAh[rbA + tm * 512];
            afl[tm] = *(const half8v*)&sAl[rbA + tm * 512];
        }
#pragma unroll
        for (int tn = 0; tn < 4; ++tn) {
            bfh[tn] = *(const half8v*)&sBh[rbB + tn * 512];
            bfl[tn] = *(const half8v*)&sBl[rbB + tn * 512];
        }
#pragma unroll
        for (int tm = 0; tm < 4; ++tm)
#pragma unroll
            for (int tn = 0; tn < 4; ++tn) {
                acch[tm][tn] = __builtin_amdgcn_mfma_f32_16x16x32_f16(afh[tm], bfh[tn], acch[tm][tn], 0, 0, 0);
                accx[tm][tn] = __builtin_amdgcn_mfma_f32_16x16x32_f16(afh[tm], bfl[tn], accx[tm][tn], 0, 0, 0);
                accx[tm][tn] = __builtin_amdgcn_mfma_f32_16x16x32_f16(afl[tm], bfh[tn], accx[tm][tn], 0, 0, 0);
            }
        __syncthreads();
        cur ^= 1;
    }
#undef STAGE_P
#pragma unroll
    for (int tm = 0; tm < 4; ++tm)
#pragma unroll
        for (int reg = 0; reg < 4; ++reg) {
            int m = m0 + wm * 64 + tm * 16 + quad * 4 + reg;
            if (m < M) {
#pragma unroll
                for (int tn = 0; tn < 4; ++tn) {
                    int n = n0 + wn * 64 + tn * 16 + l15;
                    u[(size_t)m * 1536 + n] = acch[tm][tn][reg] + accx[tm][tn][reg] * (1.0f / 4096.0f);
                }
            }
        }
}

// ---------------- pmat: P[c][tap*512+dout] = (W3_tap e_c), all 4096 codes ----------------
// k_phi skeleton, identity gather; DUAL-SPLIT output: Ph fp16 + Pl fp16 (x4096).
__global__ __launch_bounds__(256, 2) void k_pmat(const _Float16* __restrict__ eh,
        const _Float16* __restrict__ el, const _Float16* __restrict__ wh,
        const _Float16* __restrict__ wl, _Float16* __restrict__ Ph,
        _Float16* __restrict__ Pl0, _Float16* __restrict__ Pl1,
        _Float16* __restrict__ Pl2) {
    __shared__ _Float16 smem[2][4][4096] __attribute__((aligned(16)));  // 64KB
    int tid = threadIdx.x;
    int lane = tid & 63, wave = tid >> 6;
    int wm = wave >> 1, wn = wave & 1;
    int quad = lane >> 4, l15 = lane & 15;
    int m0 = blockIdx.x * 128, n0 = blockIdx.y * 128;

    int slot = lane & 3;
    int r0 = wave * 32 + (lane >> 2);
    int r1 = r0 + 16;
    int sc0 = (slot ^ ((r0 >> 1) & 3)) << 3;
    int sc1 = (slot ^ ((r1 >> 1) & 3)) << 3;
    int code0 = m0 + r0;   // identity gather
    int code1 = m0 + r1;
    const _Float16* gA0h = eh + (size_t)code0 * 512 + sc0;
    const _Float16* gA1h = eh + (size_t)code1 * 512 + sc1;
    const _Float16* gA0l = el + (size_t)code0 * 512 + sc0;
    const _Float16* gA1l = el + (size_t)code1 * 512 + sc1;
    const _Float16* gB0h = wh + (size_t)(n0 + r0) * 512 + sc0;
    const _Float16* gB1h = wh + (size_t)(n0 + r1) * 512 + sc1;
    const _Float16* gB0l = wl + (size_t)(n0 + r0) * 512 + sc0;
    const _Float16* gB1l = wl + (size_t)(n0 + r1) * 512 + sc1;
    int ld0 = wave * 1024;
    int ld1 = ld0 + 512;

    int cslot = (quad ^ ((l15 >> 1) & 3)) << 3;
    int rbA = (wm * 64 + l15) * 32 + cslot;
    int rbB = (wn * 64 + l15) * 32 + cslot;

#define STAGE_M(buf, kb) do { \
    gl2lds16(gA0h + (kb), &smem[buf][0][ld0]); \
    gl2lds16(gA1h + (kb), &smem[buf][0][ld1]); \
    gl2lds16(gA0l + (kb), &smem[buf][1][ld0]); \
    gl2lds16(gA1l + (kb), &smem[buf][1][ld1]); \
    gl2lds16(gB0h + (kb), &smem[buf][2][ld0]); \
    gl2lds16(gB1h + (kb), &smem[buf][2][ld1]); \
    gl2lds16(gB0l + (kb), &smem[buf][3][ld0]); \
    gl2lds16(gB1l + (kb), &smem[buf][3][ld1]); \
} while (0)

    floatx4 acch[4][4], accx[4][4];
#pragma unroll
    for (int i = 0; i < 4; ++i)
#pragma unroll
        for (int j = 0; j < 4; ++j)
#pragma unroll
            for (int r = 0; r < 4; ++r) { acch[i][j][r] = 0.f; accx[i][j][r] = 0.f; }

    STAGE_M(0, 0);
    __syncthreads();
    int cur = 0;
    for (int it = 0; it < 16; ++it) {
        if (it < 15) STAGE_M(cur ^ 1, (it + 1) * 32);
        const _Float16* sAh = &smem[cur][0][0];
        const _Float16* sAl = &smem[cur][1][0];
        const _Float16* sBh = &smem[cur][2][0];
        const _Float16* sBl = &smem[cur][3][0];
        half8v afh[4], afl[4], bfh[4], bfl[4];
#pragma unroll
        for (int tm = 0; tm < 4; ++tm) {
            afh[tm] = *(const half8v*)&sAh[rbA + tm * 512];
            afl[tm] = *(const half8v*)&sAl[rbA + tm * 512];
        }
#pragma unroll
        for (int tn = 0; tn < 4; ++tn) {
            bfh[tn] = *(const half8v*)&sBh[rbB + tn * 512];
            bfl[tn] = *(const half8v*)&sBl[rbB + tn * 512];
        }
#pragma unroll
        for (int tm = 0; tm < 4; ++tm)
#pragma unroll
            for (int tn = 0; tn < 4; ++tn) {
                acch[tm][tn] = __builtin_amdgcn_mfma_f32_16x16x32_f16(afh[tm], bfh[tn], acch[tm][tn], 0, 0, 0);
                accx[tm][tn] = __builtin_amdgcn_mfma_f32_16x16x32_f16(afh[tm], bfl[tn], accx[tm][tn], 0, 0, 0);
                accx[tm][tn] = __builtin_amdgcn_mfma_f32_16x16x32_f16(afl[tm], bfh[tn], accx[tm][tn], 0, 0, 0);
            }
        __syncthreads();
        cur ^= 1;
    }
#undef STAGE_M
#pragma unroll
    for (int tm = 0; tm < 4; ++tm)
#pragma unroll
        for (int reg = 0; reg < 4; ++reg) {
            int m = m0 + wm * 64 + tm * 16 + quad * 4 + reg;
            _Float16* plr = plrow(Pl0, Pl1, Pl2, m);
#pragma unroll
            for (int tn = 0; tn < 4; ++tn) {
                int n = n0 + wn * 64 + tn * 16 + l15;
                float val = acch[tm][tn][reg] + accx[tm][tn][reg] * (1.0f / 4096.0f);
                HL r = split2(val);
                Ph[(size_t)m * 1536 + n] = r.h;
                plr[n] = r.l;
            }
        }
}

// combine (s<=64, u-path): resid = rsrc - (0.5*h + 0.5*(conv+bias))
__global__ __launch_bounds__(256) void k_combine(const float* __restrict__ u,
        const float* __restrict__ embed, const unsigned long long* __restrict__ minbuf,
        const float* __restrict__ bias, const float* __restrict__ rsrc,
        float* __restrict__ resid, int s, float scale) {
    int tid = threadIdx.x;
    int m = blockIdx.x * 2 + (tid >> 7);
    int d4 = (tid & 127) << 2;
    int b = m >> 9, t = m & 511;
    int bs = b * s;
    float4 bi = *(const float4*)(bias + d4);
    float uu = ((float)t + 0.5f) * scale - 0.5f;
    float fl = floorf(uu);
    float w = uu - fl;
    int i0 = (int)fl, i1 = i0 + 1;
    i0 = min(max(i0, 0), s - 1);
    i1 = min(max(i1, 0), s - 1);
    int c0 = (int)(unsigned)minbuf[bs + i0];
    int c1 = (int)(unsigned)minbuf[bs + i1];
    float4 e0 = *(const float4*)(embed + (size_t)c0 * 512 + d4);
    float4 e1 = *(const float4*)(embed + (size_t)c1 * 512 + d4);
    float om = 1.0f - w;
    float4 h4;
    h4.x = om * e0.x + w * e1.x; h4.y = om * e0.y + w * e1.y;
    h4.z = om * e0.z + w * e1.z; h4.w = om * e0.w + w * e1.w;
    float4 conv = make_float4(0.f, 0.f, 0.f, 0.f);
#pragma unroll
    for (int tap = 0; tap < 3; ++tap) {
        int tt = t + tap - 1;
        if (tt >= 0 && tt < 512) {
            float uu2 = ((float)tt + 0.5f) * scale - 0.5f;
            float fl2 = floorf(uu2);
            float w2 = uu2 - fl2;
            int j0 = (int)fl2, j1 = j0 + 1;
            j0 = min(max(j0, 0), s - 1);
            j1 = min(max(j1, 0), s - 1);
            float4 a4 = *(const float4*)(u + (size_t)(bs + j0) * 1536 + tap * 512 + d4);
            float4 b4 = *(const float4*)(u + (size_t)(bs + j1) * 1536 + tap * 512 + d4);
            float ow = 1.0f - w2;
            conv.x += ow * a4.x + w2 * b4.x;
            conv.y += ow * a4.y + w2 * b4.y;
            conv.z += ow * a4.z + w2 * b4.z;
            conv.w += ow * a4.w + w2 * b4.w;
        }
    }
    size_t off = (size_t)m * 512 + d4;
    float4 rv = *(const float4*)(rsrc + off);
    rv.x -= 0.5f * h4.x + 0.5f * (conv.x + bi.x);
    rv.y -= 0.5f * h4.y + 0.5f * (conv.y + bi.y);
    rv.z -= 0.5f * h4.z + 0.5f * (conv.z + bi.z);
    rv.w -= 0.5f * h4.w + 0.5f * (conv.w + bi.w);
    *(float4*)(resid + off) = rv;
}

// combineP (s in {128,256,512}): conv via code-indexed dual-split P lerps.
// resid = rsrc - (0.5*h + 0.5*(conv+bias))
__global__ __launch_bounds__(256) void k_combineP(const _Float16* __restrict__ Ph,
        const _Float16* __restrict__ Pl0, const _Float16* __restrict__ Pl1,
        const _Float16* __restrict__ Pl2,
        const float* __restrict__ embed, const unsigned long long* __restrict__ minbuf,
        const float* __restrict__ bias, const float* __restrict__ rsrc,
        float* __restrict__ resid, int s, float scale) {
    int tid = threadIdx.x;
    int m = blockIdx.x * 2 + (tid >> 7);
    int d4 = (tid & 127) << 2;
    int b = m >> 9, t = m & 511;
    int bs = b * s;
    float4 bi = *(const float4*)(bias + d4);
    float uu = ((float)t + 0.5f) * scale - 0.5f;
    float fl = floorf(uu);
    float w = uu - fl;
    int i0 = (int)fl, i1 = i0 + 1;
    i0 = min(max(i0, 0), s - 1);
    i1 = min(max(i1, 0), s - 1);
    int c0 = (int)(unsigned)minbuf[bs + i0];
    int c1 = (int)(unsigned)minbuf[bs + i1];
    float4 e0 = *(const float4*)(embed + (size_t)c0 * 512 + d4);
    float4 e1 = *(const float4*)(embed + (size_t)c1 * 512 + d4);
    float om = 1.0f - w;
    float4 h4;
    h4.x = om * e0.x + w * e1.x; h4.y = om * e0.y + w * e1.y;
    h4.z = om * e0.z + w * e1.z; h4.w = om * e0.w + w * e1.w;
    float4 conv = make_float4(0.f, 0.f, 0.f, 0.f);
#pragma unroll
    for (int tap = 0; tap < 3; ++tap) {
        int tt = t + tap - 1;
        if (tt >= 0 && tt < 512) {
            float uu2 = ((float)tt + 0.5f) * scale - 0.5f;
            float fl2 = floorf(uu2);
            float w2 = uu2 - fl2;
            int j0 = (int)fl2, j1 = j0 + 1;
            j0 = min(max(j0, 0), s - 1);
            j1 = min(max(j1, 0), s - 1);
            int cc0 = (int)(unsigned)minbuf[bs + j0];
            int cc1 = (int)(unsigned)minbuf[bs + j1];
            size_t o0 = (size_t)cc0 * 1536 + tap * 512 + d4;
            size_t oseg = tap * 512 + d4;
            half4v ah = *(const half4v*)(Ph + o0);
            half4v al = *(const half4v*)(plrowc(Pl0, Pl1, Pl2, cc0) + oseg);
            half4v bh = *(const half4v*)(Ph + (size_t)cc1 * 1536 + tap * 512 + d4);
            half4v bl = *(const half4v*)(plrowc(Pl0, Pl1, Pl2, cc1) + oseg);
            float ow = 1.0f - w2;
#pragma unroll
            for (int q = 0; q < 4; ++q) {
                float av = (float)ah[q] + (float)al[q] * (1.0f / 4096.0f);
                float bv = (float)bh[q] + (float)bl[q] * (1.0f / 4096.0f);
                float* cp = q == 0 ? &conv.x : q == 1 ? &conv.y : q == 2 ? &conv.z : &conv.w;
                *cp += ow * av + w2 * bv;
            }
        }
    }
    size_t off = (size_t)m * 512 + d4;
    float4 rv = *(const float4*)(rsrc + off);
    rv.x -= 0.5f * h4.x + 0.5f * (conv.x + bi.x);
    rv.y -= 0.5f * h4.y + 0.5f * (conv.y + bi.y);
    rv.z -= 0.5f * h4.z + 0.5f * (conv.z + bi.z);
    rv.w -= 0.5f * h4.w + 0.5f * (conv.w + bi.w);
    *(float4*)(resid + off) = rv;
}

__global__ __launch_bounds__(256) void k_final(const float* __restrict__ x,
        const float* __restrict__ resid, float* __restrict__ out) {
    int gid = blockIdx.x * 256 + threadIdx.x;
    float4 xv = ((const float4*)x)[gid];
    float4 rv = ((const float4*)resid)[gid];
    float4 o;
    o.x = xv.x - rv.x; o.y = xv.y - rv.y; o.z = xv.z - rv.z; o.w = xv.w - rv.w;
    ((float4*)out)[gid] = o;
}

extern "C" void kernel_launch(void* const* d_in, const int* in_sizes, int n_in,
                              void* d_out, int out_size, void* d_ws, size_t ws_size,
                              hipStream_t stream) {
    const float* x     = (const float*)d_in[0];
    const float* embed = (const float*)d_in[1];
    const float* pw    = (const float*)d_in[2];
    const float* pb    = (const float*)d_in[3];
    float* out = (float*)d_out;

    // ws layout (floats), ~59.1 MB:
    // resid 16MB | U 16MB (zh/zl; u aliases, s<=64) | ehi/elo 8MB |
    // Wt2 hi/lo 12MB (kp0-2 rows reused as Pl segs after si=6) |
    // esq 16KB | minbuf 64KB | bm2 4MB | Pl tail 3MB
    // Ph (fp16, 12.6MB) lives in d_out (out written only by k_final).
    float* resid = (float*)d_ws;
    float* Ubase = resid + 4194304;
    _Float16* zh = (_Float16*)Ubase;
    _Float16* zl = zh + 4194304;
    float* u = Ubase;
    _Float16* ehi = (_Float16*)(Ubase + 4194304);
    _Float16* elo = ehi + 2097152;
    _Float16* whi = elo + 2097152;
    _Float16* wlo = whi + 3145728;
    float* esq = (float*)(wlo + 3145728);
    unsigned long long* minbuf = (unsigned long long*)(esq + 4096);
    unsigned long long* bm2 = (unsigned long long*)(minbuf + 8192);
    _Float16* Ph = (_Float16*)d_out;
    _Float16* Pl0 = whi;                        // rows 0..1535   (dead kp0-2)
    _Float16* Pl1 = wlo;                        // rows 1536..3071 (dead kp0-2)
    _Float16* Pl2 = (_Float16*)(bm2 + 524288);  // rows 3072..4095 (3MB tail)

    k_prep_embed<<<1024, 256, 0, stream>>>(embed, ehi, elo, esq);
    k_split_w<<<12288, 256, 0, stream>>>(pw, whi, wlo);

    const int SCv[10] = {1, 2, 4, 8, 16, 32, 64, 128, 256, 512};
    // PHI_IDX with float64-ulp tie-breaks at si=2 and si=7 (verified round 2)
    const int PIv[10] = {0, 0, 1, 1, 1, 2, 2, 3, 3, 3};
    for (int si = 0; si < 10; ++si) {
        int s = SCv[si];
        int M = 16 * s;
        int kp = PIv[si];
        int lg = __builtin_ctz((unsigned)s);
        float scale = (float)s / 512.0f;
        const float* src = (si == 0) ? x : resid;
        if (s <= 8)
            k_zmean_s<<<16 * s * 8, 256, 0, stream>>>(src, zh, zl, s, lg);
        else
            k_zmean<<<(M * 512) / 256, 256, 0, stream>>>(src, zh, zl, s, lg);
        k_dist1<<<dim3((M + 127) / 128, 32), 256, 0, stream>>>(zh, ehi, esq, bm2, M);
        k_refine<<<(M + 3) / 4, 256, 0, stream>>>(zh, zl, embed, bm2, minbuf, M);
        if (si <= 6) {
            k_phi<<<dim3((M + 127) / 128, 12), 256, 0, stream>>>(ehi, elo,
                    whi + (size_t)kp * 1536 * 512, wlo + (size_t)kp * 1536 * 512, minbuf, u, M);
            k_combine<<<4096, 256, 0, stream>>>(u, embed, minbuf, pb + kp * 512, src, resid, s, scale);
        } else {
            if (si == 7)
                k_pmat<<<dim3(32, 12), 256, 0, stream>>>(ehi, elo,
                        whi + (size_t)3 * 1536 * 512, wlo + (size_t)3 * 1536 * 512,
                        Ph, Pl0, Pl1, Pl2);
            k_combineP<<<4096, 256, 0, stream>>>(Ph, Pl0, Pl1, Pl2, embed, minbuf,
                    pb + 3 * 512, src, resid, s, scale);
        }
    }
    k_final<<<4096, 256, 0, stream>>>(x, resid, out);
}

// Round 11
// 700.195 us; speedup vs baseline: 1.2096x; 1.0568x over previous
//
#include <hip/hip_runtime.h>

// Multiscale Residual VQ (VAR-style), MI355X gfx950.
// Round 16:
//   - k_dist1 epilogue: top-2 butterfly via DPP row_ror (0x121/2/4/8) instead
//     of __shfl_xor. The u64 shuffles were 256 ds_bpermute/thread (~1500cyc,
//     the measured VALUBusy-39%/32768-bank-conflict blob). ror-1,2,4,8 is a
//     disjoint-coverage reduce tree within each 16-lane DPP row (= the l15
//     group), all 64 packed values distinct -> identical (best,second).
//   - k_combineP: s==512 fast path (w2==0 exactly) skips the second P gather
//     per tap (conv += av is bit-identical to ow*av+0*bv).
// Everything else unchanged from round 15 (740us passing).

#define ND 512
#define NCB 4096
#define DELTA 0.5f

typedef _Float16 half8v __attribute__((ext_vector_type(8)));
typedef _Float16 half4v __attribute__((ext_vector_type(4)));
typedef float floatx4 __attribute__((ext_vector_type(4)));

struct HL { _Float16 h, l; };

__device__ __forceinline__ HL split2(float v) {
    HL r;
    r.h = (_Float16)v;
    r.l = (_Float16)((v - (float)r.h) * 4096.0f);
    return r;
}

__device__ __forceinline__ unsigned long long pack_dist(float d, int n) {
    unsigned u = __float_as_uint(d);
    u = (u & 0x80000000u) ? ~u : (u | 0x80000000u);   // monotone total order
    return ((unsigned long long)u << 32) | (unsigned)n; // tie -> lowest idx
}

__device__ __forceinline__ float unpack_dist(unsigned long long p) {
    unsigned u = (unsigned)(p >> 32);
    u = (u & 0x80000000u) ? (u & 0x7fffffffu) : ~u;
    return __uint_as_float(u);
}

// u64 DPP row_ror move (ctrl must be literal); bound_ctrl=1, full masks.
#define DPP_ROR64(dst, src, CTRL) do { \
    unsigned lo_ = (unsigned)(src), hi_ = (unsigned)((src) >> 32); \
    lo_ = (unsigned)__builtin_amdgcn_update_dpp(0, (int)lo_, (CTRL), 0xF, 0xF, true); \
    hi_ = (unsigned)__builtin_amdgcn_update_dpp(0, (int)hi_, (CTRL), 0xF, 0xF, true); \
    (dst) = ((unsigned long long)hi_ << 32) | lo_; \
} while (0)

// async global->LDS, 16B per lane; LDS dest = wave-uniform base + lane*16
__device__ __forceinline__ void gl2lds16(const _Float16* g, _Float16* l) {
    __builtin_amdgcn_global_load_lds(
        (const __attribute__((address_space(1))) unsigned int*)g,
        (__attribute__((address_space(3))) unsigned int*)l, 16, 0, 0);
}

// Pl row c lives in one of three segments (whi-dead, wlo-dead, ws tail)
__device__ __forceinline__ _Float16* plrow(_Float16* p0, _Float16* p1,
                                           _Float16* p2, int c) {
    return c < 1536 ? p0 + (size_t)c * 1536
         : c < 3072 ? p1 + (size_t)(c - 1536) * 1536
                    : p2 + (size_t)(c - 3072) * 1536;
}
__device__ __forceinline__ const _Float16* plrowc(const _Float16* p0,
        const _Float16* p1, const _Float16* p2, int c) {
    return c < 1536 ? p0 + (size_t)c * 1536
         : c < 3072 ? p1 + (size_t)(c - 1536) * 1536
                    : p2 + (size_t)(c - 3072) * 1536;
}

// embed -> ehi/elo halves + esq (fused single pass over embed)
__global__ __launch_bounds__(256) void k_prep_embed(const float* __restrict__ embed,
        _Float16* __restrict__ eh, _Float16* __restrict__ el, float* __restrict__ esq) {
    int c = blockIdx.x * 4 + (threadIdx.x >> 6);    // 1024 blocks
    int lane = threadIdx.x & 63;
    const float* row = embed + (size_t)c * ND + lane * 8;
    float4 v0 = *(const float4*)row;
    float4 v1 = *(const float4*)(row + 4);
    float vs[8] = {v0.x, v0.y, v0.z, v0.w, v1.x, v1.y, v1.z, v1.w};
    half8v h8, l8;
    double acc = 0.0;
#pragma unroll
    for (int i = 0; i < 8; ++i) {
        HL r = split2(vs[i]);
        h8[i] = r.h; l8[i] = r.l;
        acc += (double)vs[i] * (double)vs[i];
    }
    *(half8v*)(eh + (size_t)c * ND + lane * 8) = h8;
    *(half8v*)(el + (size_t)c * ND + lane * 8) = l8;
#pragma unroll
    for (int off = 32; off > 0; off >>= 1) acc += __shfl_down(acc, off, 64);
    if (lane == 0) esq[c] = (float)acc;
}

// Wt2[kp][tap*512+dout][din] hi/lo from pw[kp][dout][din][tap]; output-indexed
__global__ __launch_bounds__(256) void k_split_w(const float* __restrict__ pw,
        _Float16* __restrict__ wh, _Float16* __restrict__ wl) {
    int gid = blockIdx.x * 256 + threadIdx.x;       // 4*1536*512 = 3,145,728
    int din = gid & 511;
    int nn = (gid >> 9) % 1536;
    int kp = gid / (512 * 1536);
    int tap = nn >> 9;
    int dout = nn & 511;
    float v = pw[(((size_t)(kp * 512 + dout) * 512) + din) * 3 + tap];
    HL r = split2(v);
    wh[gid] = r.h;
    wl[gid] = r.l;
}

// z[b,j,d] = block mean of src (fp64 acc) -> split halves zh/zl  (s >= 16)
__global__ __launch_bounds__(256) void k_zmean(const float* __restrict__ src,
        _Float16* __restrict__ zh, _Float16* __restrict__ zl, int s, int lg) {
    int gid = blockIdx.x * 256 + threadIdx.x;       // 16*s*512 threads
    int d = gid & 511;
    int j = (gid >> 9) & (s - 1);
    int b = gid >> (9 + lg);
    int r = 512 >> lg;
    const float* p = src + ((size_t)((b << 9) + (j << (9 - lg))) << 9) + d;
    double acc = 0.0;
#pragma unroll 4
    for (int m = 0; m < r; ++m) acc += (double)p[(size_t)m * ND];
    float v = (float)(acc * (1.0 / (double)r));
    HL hl = split2(v);
    zh[gid] = hl.h;
    zl[gid] = hl.l;
}

// small-s zmean (s <= 8, r = 512/s >= 64): 4-way row-split per 16-lane d-group,
// deterministic shuffle tree ((a0+a2)+(a1+a3)); 8-32x more workgroups.
__global__ __launch_bounds__(256) void k_zmean_s(const float* __restrict__ src,
        _Float16* __restrict__ zh, _Float16* __restrict__ zl, int s, int lg) {
    int bj = blockIdx.x >> 3;          // (b*s + j)
    int dblk = blockIdx.x & 7;
    int b = bj >> lg;
    int j = bj & (s - 1);
    int wave = threadIdx.x >> 6, lane = threadIdx.x & 63;
    int rg = lane >> 4;                // 0..3 row-group
    int dl = lane & 15;
    int d = dblk * 64 + wave * 16 + dl;
    int r = 512 >> lg;
    const float* p = src + ((size_t)((b << 9) + (j << (9 - lg))) << 9) + d;
    double acc = 0.0;
    for (int k = rg; k < r; k += 4) acc += (double)p[(size_t)k * ND];
    acc += __shfl_down(acc, 32, 64);   // rg0+=rg2, rg1+=rg3
    acc += __shfl_down(acc, 16, 64);   // rg0+=rg1'
    if (rg == 0) {
        float v = (float)(acc * (1.0 / (double)r));
        HL hl = split2(v);
        size_t gi = ((size_t)bj << 9) + d;
        zh[gi] = hl.h;
        zl[gi] = hl.l;
    }
}

// ---------------- dist pass 1: hh-only GEMM, 128x128 block, 2x2 waves ----------------
// epilogue: per-(m, n-block) top-2 packed (dist,idx) -> bm2[m][32][2], no atomics
__global__ __launch_bounds__(256, 4) void k_dist1(const _Float16* __restrict__ zh,
        const _Float16* __restrict__ eh, const float* __restrict__ esq,
        unsigned long long* __restrict__ bm2, int M) {
    __shared__ _Float16 smem[2][2][4096] __attribute__((aligned(16)));  // 32 KB
    // epilogue alias (live only after the main loop's trailing barrier): 4 KB
    unsigned long long (*packs2)[2][2] =
        reinterpret_cast<unsigned long long(*)[2][2]>(&smem[0][0][0]);
    int tid = threadIdx.x;
    int lane = tid & 63, wave = tid >> 6;
    int wm = wave >> 1, wn = wave & 1;
    int quad = lane >> 4, l15 = lane & 15;
    int m0 = blockIdx.x * 128, n0 = blockIdx.y * 128;

    int slot = lane & 3;
    int r0 = wave * 32 + (lane >> 2);
    int r1 = r0 + 16;
    int sc0 = (slot ^ ((r0 >> 1) & 3)) << 3;    // swizzled source col (halves)
    int sc1 = (slot ^ ((r1 >> 1) & 3)) << 3;
    int a0 = m0 + r0; if (a0 >= M) a0 = M - 1;
    int a1 = m0 + r1; if (a1 >= M) a1 = M - 1;
    const _Float16* gA0 = zh + (size_t)a0 * 512 + sc0;
    const _Float16* gA1 = zh + (size_t)a1 * 512 + sc1;
    const _Float16* gB0 = eh + (size_t)(n0 + r0) * 512 + sc0;
    const _Float16* gB1 = eh + (size_t)(n0 + r1) * 512 + sc1;
    int ld0 = wave * 1024, ld1 = ld0 + 512;

    int cslot = (quad ^ ((l15 >> 1) & 3)) << 3;
    int rbA = (wm * 64 + l15) * 32 + cslot;
    int rbB = (wn * 64 + l15) * 32 + cslot;

#define STG(buf, kb) do { \
    gl2lds16(gA0 + (kb), &smem[buf][0][ld0]); \
    gl2lds16(gA1 + (kb), &smem[buf][0][ld1]); \
    gl2lds16(gB0 + (kb), &smem[buf][1][ld0]); \
    gl2lds16(gB1 + (kb), &smem[buf][1][ld1]); \
} while (0)

    floatx4 acc[4][4];
#pragma unroll
    for (int i = 0; i < 4; ++i)
#pragma unroll
        for (int j = 0; j < 4; ++j)
#pragma unroll
            for (int r = 0; r < 4; ++r) acc[i][j][r] = 0.f;

    STG(0, 0);
    __syncthreads();
    int cur = 0;
    for (int it = 0; it < 16; ++it) {
        if (it < 15) STG(cur ^ 1, (it + 1) * 32);
        const _Float16* sA = &smem[cur][0][0];
        const _Float16* sB = &smem[cur][1][0];
        half8v af[4], bf[4];
#pragma unroll
        for (int tm = 0; tm < 4; ++tm) af[tm] = *(const half8v*)&sA[rbA + tm * 512];
#pragma unroll
        for (int tn = 0; tn < 4; ++tn) bf[tn] = *(const half8v*)&sB[rbB + tn * 512];
#pragma unroll
        for (int tm = 0; tm < 4; ++tm)
#pragma unroll
            for (int tn = 0; tn < 4; ++tn)
                acc[tm][tn] = __builtin_amdgcn_mfma_f32_16x16x32_f16(af[tm], bf[tn], acc[tm][tn], 0, 0, 0);
        __syncthreads();
        cur ^= 1;
    }
#undef STG
    float es[4];
#pragma unroll
    for (int tn = 0; tn < 4; ++tn) es[tn] = esq[n0 + wn * 64 + tn * 16 + l15];
    // per-(m, half-block) top-2 reduction via DPP row_ror tree, zero ds ops
#pragma unroll
    for (int tm = 0; tm < 4; ++tm)
#pragma unroll
        for (int reg = 0; reg < 4; ++reg) {
            unsigned long long b = ~0ull, sd = ~0ull;
#pragma unroll
            for (int tn = 0; tn < 4; ++tn) {
                float dd = fmaf(-2.f, acc[tm][tn][reg], es[tn]);
                int n = n0 + wn * 64 + tn * 16 + l15;
                unsigned long long p = pack_dist(dd, n);
                if (p < b) { sd = b; b = p; } else if (p < sd) sd = p;
            }
            // ror 1,2,4,8: disjoint-coverage reduce over the 16-lane DPP row
            {
                unsigned long long ob, os, mx, mn2;
                DPP_ROR64(ob, b, 0x121); DPP_ROR64(os, sd, 0x121);
                mx = b > ob ? b : ob; b = b < ob ? b : ob;
                mn2 = sd < os ? sd : os; sd = mx < mn2 ? mx : mn2;
                DPP_ROR64(ob, b, 0x122); DPP_ROR64(os, sd, 0x122);
                mx = b > ob ? b : ob; b = b < ob ? b : ob;
                mn2 = sd < os ? sd : os; sd = mx < mn2 ? mx : mn2;
                DPP_ROR64(ob, b, 0x124); DPP_ROR64(os, sd, 0x124);
                mx = b > ob ? b : ob; b = b < ob ? b : ob;
                mn2 = sd < os ? sd : os; sd = mx < mn2 ? mx : mn2;
                DPP_ROR64(ob, b, 0x128); DPP_ROR64(os, sd, 0x128);
                mx = b > ob ? b : ob; b = b < ob ? b : ob;
                mn2 = sd < os ? sd : os; sd = mx < mn2 ? mx : mn2;
            }
            if (l15 == 0) {
                packs2[wm * 64 + tm * 16 + quad * 4 + reg][wn][0] = b;
                packs2[wm * 64 + tm * 16 + quad * 4 + reg][wn][1] = sd;
            }
        }
    __syncthreads();
    if (tid < 128) {
        unsigned long long b0 = packs2[tid][0][0], s0 = packs2[tid][0][1];
        unsigned long long b1 = packs2[tid][1][0], s1 = packs2[tid][1][1];
        unsigned long long b = b0 < b1 ? b0 : b1;
        unsigned long long mx = b0 > b1 ? b0 : b1;
        unsigned long long mn2 = s0 < s1 ? s0 : s1;
        unsigned long long sd = mx < mn2 ? mx : mn2;
        size_t idx = ((size_t)(m0 + tid) * 32 + blockIdx.y) * 2;
        bm2[idx] = b;
        bm2[idx + 1] = sd;
    }
}

// ---------------- dist pass 2: exact refine over 64 gathered candidates ----------------
__global__ __launch_bounds__(256) void k_refine(const _Float16* __restrict__ zh,
        const _Float16* __restrict__ zl, const float* __restrict__ embed,
        const unsigned long long* __restrict__ bm2,
        unsigned long long* __restrict__ minbuf, int M) {
    int lane = threadIdx.x & 63, wave = threadIdx.x >> 6;
    int m = blockIdx.x * 4 + wave;
    if (m >= M) return;
    float zr[8];
    const _Float16* ph = zh + (size_t)m * 512 + lane * 8;
    const _Float16* pl = zl + (size_t)m * 512 + lane * 8;
#pragma unroll
    for (int i = 0; i < 8; ++i)
        zr[i] = (float)ph[i] + (float)pl[i] * (1.0f / 4096.0f);
    unsigned long long p = bm2[(size_t)m * 64 + lane];
    unsigned long long mn = p;
#pragma unroll
    for (int off = 1; off < 64; off <<= 1) {
        unsigned long long q = __shfl_xor(mn, off, 64);
        mn = q < mn ? q : mn;
    }
    float T = unpack_dist(mn) + DELTA;
    unsigned long long mask = __ballot(unpack_dist(p) <= T);
    double bestD = 1e300;
    int bestI = 0x7fffffff;
    while (mask) {
        int bit = __ffsll((unsigned long long)mask) - 1;
        mask &= mask - 1;
        int idx = (int)(unsigned)__shfl(p, bit, 64);
        const float* e = embed + (size_t)idx * 512 + lane * 8;
        double s = 0.0;
#pragma unroll
        for (int i = 0; i < 8; ++i) {
            double df = (double)zr[i] - (double)e[i];
            s += df * df;
        }
#pragma unroll
        for (int off = 32; off > 0; off >>= 1) s += __shfl_down(s, off, 64);
        if (lane == 0) {
            if (s < bestD || (s == bestD && idx < bestI)) { bestD = s; bestI = idx; }
        }
    }
    if (lane == 0) minbuf[m] = (unsigned long long)(unsigned)bestI;
}

// ---------------- phi (s<=64): u[m][tap*512+dout] = (W_tap q_m)[dout] ----------------
__global__ __launch_bounds__(256, 2) void k_phi(const _Float16* __restrict__ eh,
        const _Float16* __restrict__ el, const _Float16* __restrict__ wh,
        const _Float16* __restrict__ wl, const unsigned long long* __restrict__ minbuf,
        float* __restrict__ u, int M) {
    __shared__ _Float16 smem[2][4][4096] __attribute__((aligned(16)));  // 64KB exactly
    int* idxs = reinterpret_cast<int*>(&smem[0][0][0]);
    int tid = threadIdx.x;
    int lane = tid & 63, wave = tid >> 6;
    int wm = wave >> 1, wn = wave & 1;
    int quad = lane >> 4, l15 = lane & 15;
    int m0 = blockIdx.x * 128, n0 = blockIdx.y * 128;
    if (tid < 128) {
        int m = m0 + tid; if (m >= M) m = M - 1;
        idxs[tid] = (int)(unsigned)minbuf[m];
    }
    __syncthreads();

    int slot = lane & 3;
    int r0 = wave * 32 + (lane >> 2);
    int r1 = r0 + 16;
    int sc0 = (slot ^ ((r0 >> 1) & 3)) << 3;
    int sc1 = (slot ^ ((r1 >> 1) & 3)) << 3;
    int code0 = idxs[r0];
    int code1 = idxs[r1];
    __syncthreads();   // all waves done reading idxs before DMA overwrites smem
    const _Float16* gA0h = eh + (size_t)code0 * 512 + sc0;
    const _Float16* gA1h = eh + (size_t)code1 * 512 + sc1;
    const _Float16* gA0l = el + (size_t)code0 * 512 + sc0;
    const _Float16* gA1l = el + (size_t)code1 * 512 + sc1;
    const _Float16* gB0h = wh + (size_t)(n0 + r0) * 512 + sc0;
    const _Float16* gB1h = wh + (size_t)(n0 + r1) * 512 + sc1;
    const _Float16* gB0l = wl + (size_t)(n0 + r0) * 512 + sc0;
    const _Float16* gB1l = wl + (size_t)(n0 + r1) * 512 + sc1;
    int ld0 = wave * 1024;
    int ld1 = ld0 + 512;

    int cslot = (quad ^ ((l15 >> 1) & 3)) << 3;
    int rbA = (wm * 64 + l15) * 32 + cslot;
    int rbB = (wn * 64 + l15) * 32 + cslot;

#define STAGE_P(buf, kb) do { \
    gl2lds16(gA0h + (kb), &smem[buf][0][ld0]); \
    gl2lds16(gA1h + (kb), &smem[buf][0][ld1]); \
    gl2lds16(gA0l + (kb), &smem[buf][1][ld0]); \
    gl2lds16(gA1l + (kb), &smem[buf][1][ld1]); \
    gl2lds16(gB0h + (kb), &smem[buf][2][ld0]); \
    gl2lds16(gB1h + (kb), &smem[buf][2][ld1]); \
    gl2lds16(gB0l + (kb), &smem[buf][3][ld0]); \
    gl2lds16(gB1l + (kb), &smem[buf][3][ld1]); \
} while (0)

    floatx4 acch[4][4], accx[4][4];
#pragma unroll
    for (int i = 0; i < 4; ++i)
#pragma unroll
        for (int j = 0; j < 4; ++j)
#pragma unroll
            for (int r = 0; r < 4; ++r) { acch[i][j][r] = 0.f; accx[i][j][r] = 0.f; }

    STAGE_P(0, 0);
    __syncthreads();
    int cur = 0;
    for (int it = 0; it < 16; ++it) {
        if (it < 15) STAGE_P(cur ^ 1, (it + 1) * 32);
        const _Float16* sAh = &smem[cur][0][0];
        const _Float16* sAl = &smem[cur][1][0];
        const _Float16* sBh = &smem[cur][2][0];
        const _Float16* sBl = &smem[cur][3][0];
        half8v afh[4], afl[4], bfh[4], bfl[4];
#pragma unroll
        for (int tm = 0; tm < 4; ++tm) {
            afh[tm] = *(const half8v*)&sAh[rbA + tm * 512];
            afl[tm] = *(const half8v*)&sAl[rbA + tm * 512];
        }
#pragma unroll
        for (int tn = 0; tn < 4; ++tn) {
            bfh[tn] = *(const half8v*)&sBh[rbB + tn * 512];
            bfl[tn] = *(const half8v*)&sBl[rbB + tn * 512];
        }
#pragma unroll
        for (int tm = 0; tm < 4; ++tm)
#pragma unroll
            for (int tn = 0; tn < 4; ++tn) {
                acch[tm][tn] = __builtin_amdgcn_mfma_f32_16x16x32_f16(afh[tm], bfh[tn], acch[tm][tn], 0, 0, 0);
                accx[tm][tn] = __builtin_amdgcn_mfma_f32_16x16x32_f16(afh[tm], bfl[tn], accx[tm][tn], 0, 0, 0);
                accx[tm][tn] = __builtin_amdgcn_mfma_f32_16x16x32_f16(afl[tm], bfh[tn], accx[tm][tn], 0, 0, 0);
            }
        __syncthreads();
        cur ^= 1;
    }
#undef STAGE_P
#pragma unroll
    for (int tm = 0; tm < 4; ++tm)
#pragma unroll
        for (int reg = 0; reg < 4; ++reg) {
            int m = m0 + wm * 64 + tm * 16 + quad * 4 + reg;
            if (m < M) {
#pragma unroll
                for (int tn = 0; tn < 4; ++tn) {
                    int n = n0 + wn * 64 + tn * 16 + l15;
                    u[(size_t)m * 1536 + n] = acch[tm][tn][reg] + accx[tm][tn][reg] * (1.0f / 4096.0f);
                }
            }
        }
}

// ---------------- pmat: P[c][tap*512+dout] = (W3_tap e_c), all 4096 codes ----------------
// k_phi skeleton, identity gather; DUAL-SPLIT output: Ph fp16 + Pl fp16 (x4096).
__global__ __launch_bounds__(256, 2) void k_pmat(const _Float16* __restrict__ eh,
        const _Float16* __restrict__ el, const _Float16* __restrict__ wh,
        const _Float16* __restrict__ wl, _Float16* __restrict__ Ph,
        _Float16* __restrict__ Pl0, _Float16* __restrict__ Pl1,
        _Float16* __restrict__ Pl2) {
    __shared__ _Float16 smem[2][4][4096] __attribute__((aligned(16)));  // 64KB
    int tid = threadIdx.x;
    int lane = tid & 63, wave = tid >> 6;
    int wm = wave >> 1, wn = wave & 1;
    int quad = lane >> 4, l15 = lane & 15;
    int m0 = blockIdx.x * 128, n0 = blockIdx.y * 128;

    int slot = lane & 3;
    int r0 = wave * 32 + (lane >> 2);
    int r1 = r0 + 16;
    int sc0 = (slot ^ ((r0 >> 1) & 3)) << 3;
    int sc1 = (slot ^ ((r1 >> 1) & 3)) << 3;
    int code0 = m0 + r0;   // identity gather
    int code1 = m0 + r1;
    const _Float16* gA0h = eh + (size_t)code0 * 512 + sc0;
    const _Float16* gA1h = eh + (size_t)code1 * 512 + sc1;
    const _Float16* gA0l = el + (size_t)code0 * 512 + sc0;
    const _Float16* gA1l = el + (size_t)code1 * 512 + sc1;
    const _Float16* gB0h = wh + (size_t)(n0 + r0) * 512 + sc0;
    const _Float16* gB1h = wh + (size_t)(n0 + r1) * 512 + sc1;
    const _Float16* gB0l = wl + (size_t)(n0 + r0) * 512 + sc0;
    const _Float16* gB1l = wl + (size_t)(n0 + r1) * 512 + sc1;
    int ld0 = wave * 1024;
    int ld1 = ld0 + 512;

    int cslot = (quad ^ ((l15 >> 1) & 3)) << 3;
    int rbA = (wm * 64 + l15) * 32 + cslot;
    int rbB = (wn * 64 + l15) * 32 + cslot;

#define STAGE_M(buf, kb) do { \
    gl2lds16(gA0h + (kb), &smem[buf][0][ld0]); \
    gl2lds16(gA1h + (kb), &smem[buf][0][ld1]); \
    gl2lds16(gA0l + (kb), &smem[buf][1][ld0]); \
    gl2lds16(gA1l + (kb), &smem[buf][1][ld1]); \
    gl2lds16(gB0h + (kb), &smem[buf][2][ld0]); \
    gl2lds16(gB1h + (kb), &smem[buf][2][ld1]); \
    gl2lds16(gB0l + (kb), &smem[buf][3][ld0]); \
    gl2lds16(gB1l + (kb), &smem[buf][3][ld1]); \
} while (0)

    floatx4 acch[4][4], accx[4][4];
#pragma unroll
    for (int i = 0; i < 4; ++i)
#pragma unroll
        for (int j = 0; j < 4; ++j)
#pragma unroll
            for (int r = 0; r < 4; ++r) { acch[i][j][r] = 0.f; accx[i][j][r] = 0.f; }

    STAGE_M(0, 0);
    __syncthreads();
    int cur = 0;
    for (int it = 0; it < 16; ++it) {
        if (it < 15) STAGE_M(cur ^ 1, (it + 1) * 32);
        const _Float16* sAh = &smem[cur][0][0];
        const _Float16* sAl = &smem[cur][1][0];
        const _Float16* sBh = &smem[cur][2][0];
        const _Float16* sBl = &smem[cur][3][0];
        half8v afh[4], afl[4], bfh[4], bfl[4];
#pragma unroll
        for (int tm = 0; tm < 4; ++tm) {
            afh[tm] = *(const half8v*)&sAh[rbA + tm * 512];
            afl[tm] = *(const half8v*)&sAl[rbA + tm * 512];
        }
#pragma unroll
        for (int tn = 0; tn < 4; ++tn) {
            bfh[tn] = *(const half8v*)&sBh[rbB + tn * 512];
            bfl[tn] = *(const half8v*)&sBl[rbB + tn * 512];
        }
#pragma unroll
        for (int tm = 0; tm < 4; ++tm)
#pragma unroll
            for (int tn = 0; tn < 4; ++tn) {
                acch[tm][tn] = __builtin_amdgcn_mfma_f32_16x16x32_f16(afh[tm], bfh[tn], acch[tm][tn], 0, 0, 0);
                accx[tm][tn] = __builtin_amdgcn_mfma_f32_16x16x32_f16(afh[tm], bfl[tn], accx[tm][tn], 0, 0, 0);
                accx[tm][tn] = __builtin_amdgcn_mfma_f32_16x16x32_f16(afl[tm], bfh[tn], accx[tm][tn], 0, 0, 0);
            }
        __syncthreads();
        cur ^= 1;
    }
#undef STAGE_M
#pragma unroll
    for (int tm = 0; tm < 4; ++tm)
#pragma unroll
        for (int reg = 0; reg < 4; ++reg) {
            int m = m0 + wm * 64 + tm * 16 + quad * 4 + reg;
            _Float16* plr = plrow(Pl0, Pl1, Pl2, m);
#pragma unroll
            for (int tn = 0; tn < 4; ++tn) {
                int n = n0 + wn * 64 + tn * 16 + l15;
                float val = acch[tm][tn][reg] + accx[tm][tn][reg] * (1.0f / 4096.0f);
                HL r = split2(val);
                Ph[(size_t)m * 1536 + n] = r.h;
                plr[n] = r.l;
            }
        }
}

// combine (s<=64, u-path): resid = rsrc - (0.5*h + 0.5*(conv+bias))
__global__ __launch_bounds__(256) void k_combine(const float* __restrict__ u,
        const float* __restrict__ embed, const unsigned long long* __restrict__ minbuf,
        const float* __restrict__ bias, const float* __restrict__ rsrc,
        float* __restrict__ resid, int s, float scale) {
    int tid = threadIdx.x;
    int m = blockIdx.x * 2 + (tid >> 7);
    int d4 = (tid & 127) << 2;
    int b = m >> 9, t = m & 511;
    int bs = b * s;
    float4 bi = *(const float4*)(bias + d4);
    float uu = ((float)t + 0.5f) * scale - 0.5f;
    float fl = floorf(uu);
    float w = uu - fl;
    int i0 = (int)fl, i1 = i0 + 1;
    i0 = min(max(i0, 0), s - 1);
    i1 = min(max(i1, 0), s - 1);
    int c0 = (int)(unsigned)minbuf[bs + i0];
    int c1 = (int)(unsigned)minbuf[bs + i1];
    float4 e0 = *(const float4*)(embed + (size_t)c0 * 512 + d4);
    float4 e1 = *(const float4*)(embed + (size_t)c1 * 512 + d4);
    float om = 1.0f - w;
    float4 h4;
    h4.x = om * e0.x + w * e1.x; h4.y = om * e0.y + w * e1.y;
    h4.z = om * e0.z + w * e1.z; h4.w = om * e0.w + w * e1.w;
    float4 conv = make_float4(0.f, 0.f, 0.f, 0.f);
#pragma unroll
    for (int tap = 0; tap < 3; ++tap) {
        int tt = t + tap - 1;
        if (tt >= 0 && tt < 512) {
            float uu2 = ((float)tt + 0.5f) * scale - 0.5f;
            float fl2 = floorf(uu2);
            float w2 = uu2 - fl2;
            int j0 = (int)fl2, j1 = j0 + 1;
            j0 = min(max(j0, 0), s - 1);
            j1 = min(max(j1, 0), s - 1);
            float4 a4 = *(const float4*)(u + (size_t)(bs + j0) * 1536 + tap * 512 + d4);
            float4 b4 = *(const float4*)(u + (size_t)(bs + j1) * 1536 + tap * 512 + d4);
            float ow = 1.0f - w2;
            conv.x += ow * a4.x + w2 * b4.x;
            conv.y += ow * a4.y + w2 * b4.y;
            conv.z += ow * a4.z + w2 * b4.z;
            conv.w += ow * a4.w + w2 * b4.w;
        }
    }
    size_t off = (size_t)m * 512 + d4;
    float4 rv = *(const float4*)(rsrc + off);
    rv.x -= 0.5f * h4.x + 0.5f * (conv.x + bi.x);
    rv.y -= 0.5f * h4.y + 0.5f * (conv.y + bi.y);
    rv.z -= 0.5f * h4.z + 0.5f * (conv.z + bi.z);
    rv.w -= 0.5f * h4.w + 0.5f * (conv.w + bi.w);
    *(float4*)(resid + off) = rv;
}

// combineP (s in {128,256,512}): conv via code-indexed dual-split P lerps.
// resid = rsrc - (0.5*h + 0.5*(conv+bias)); s==512 -> w2==0, single gather.
__global__ __launch_bounds__(256) void k_combineP(const _Float16* __restrict__ Ph,
        const _Float16* __restrict__ Pl0, const _Float16* __restrict__ Pl1,
        const _Float16* __restrict__ Pl2,
        const float* __restrict__ embed, const unsigned long long* __restrict__ minbuf,
        const float* __restrict__ bias, const float* __restrict__ rsrc,
        float* __restrict__ resid, int s, float scale) {
    int tid = threadIdx.x;
    int m = blockIdx.x * 2 + (tid >> 7);
    int d4 = (tid & 127) << 2;
    int b = m >> 9, t = m & 511;
    int bs = b * s;
    int noint = (s == 512);
    float4 bi = *(const float4*)(bias + d4);
    float uu = ((float)t + 0.5f) * scale - 0.5f;
    float fl = floorf(uu);
    float w = uu - fl;
    int i0 = (int)fl, i1 = i0 + 1;
    i0 = min(max(i0, 0), s - 1);
    i1 = min(max(i1, 0), s - 1);
    int c0 = (int)(unsigned)minbuf[bs + i0];
    int c1 = (int)(unsigned)minbuf[bs + i1];
    float4 e0 = *(const float4*)(embed + (size_t)c0 * 512 + d4);
    float4 e1 = *(const float4*)(embed + (size_t)c1 * 512 + d4);
    float om = 1.0f - w;
    float4 h4;
    h4.x = om * e0.x + w * e1.x; h4.y = om * e0.y + w * e1.y;
    h4.z = om * e0.z + w * e1.z; h4.w = om * e0.w + w * e1.w;
    float4 conv = make_float4(0.f, 0.f, 0.f, 0.f);
#pragma unroll
    for (int tap = 0; tap < 3; ++tap) {
        int tt = t + tap - 1;
        if (tt >= 0 && tt < 512) {
            float uu2 = ((float)tt + 0.5f) * scale - 0.5f;
            float fl2 = floorf(uu2);
            float w2 = uu2 - fl2;
            int j0 = (int)fl2, j1 = j0 + 1;
            j0 = min(max(j0, 0), s - 1);
            j1 = min(max(j1, 0), s - 1);
            int cc0 = (int)(unsigned)minbuf[bs + j0];
            size_t oseg = tap * 512 + d4;
            half4v ah = *(const half4v*)(Ph + (size_t)cc0 * 1536 + oseg);
            half4v al = *(const half4v*)(plrowc(Pl0, Pl1, Pl2, cc0) + oseg);
            if (noint) {
                // w2 == 0 exactly: conv += av
#pragma unroll
                for (int q = 0; q < 4; ++q) {
                    float av = (float)ah[q] + (float)al[q] * (1.0f / 4096.0f);
                    float* cp = q == 0 ? &conv.x : q == 1 ? &conv.y : q == 2 ? &conv.z : &conv.w;
                    *cp += av;
                }
            } else {
                int cc1 = (int)(unsigned)minbuf[bs + j1];
                half4v bh = *(const half4v*)(Ph + (size_t)cc1 * 1536 + oseg);
                half4v bl = *(const half4v*)(plrowc(Pl0, Pl1, Pl2, cc1) + oseg);
                float ow = 1.0f - w2;
#pragma unroll
                for (int q = 0; q < 4; ++q) {
                    float av = (float)ah[q] + (float)al[q] * (1.0f / 4096.0f);
                    float bv = (float)bh[q] + (float)bl[q] * (1.0f / 4096.0f);
                    float* cp = q == 0 ? &conv.x : q == 1 ? &conv.y : q == 2 ? &conv.z : &conv.w;
                    *cp += ow * av + w2 * bv;
                }
            }
        }
    }
    size_t off = (size_t)m * 512 + d4;
    float4 rv = *(const float4*)(rsrc + off);
    rv.x -= 0.5f * h4.x + 0.5f * (conv.x + bi.x);
    rv.y -= 0.5f * h4.y + 0.5f * (conv.y + bi.y);
    rv.z -= 0.5f * h4.z + 0.5f * (conv.z + bi.z);
    rv.w -= 0.5f * h4.w + 0.5f * (conv.w + bi.w);
    *(float4*)(resid + off) = rv;
}

__global__ __launch_bounds__(256) void k_final(const float* __restrict__ x,
        const float* __restrict__ resid, float* __restrict__ out) {
    int gid = blockIdx.x * 256 + threadIdx.x;
    float4 xv = ((const float4*)x)[gid];
    float4 rv = ((const float4*)resid)[gid];
    float4 o;
    o.x = xv.x - rv.x; o.y = xv.y - rv.y; o.z = xv.z - rv.z; o.w = xv.w - rv.w;
    ((float4*)out)[gid] = o;
}

extern "C" void kernel_launch(void* const* d_in, const int* in_sizes, int n_in,
                              void* d_out, int out_size, void* d_ws, size_t ws_size,
                              hipStream_t stream) {
    const float* x     = (const float*)d_in[0];
    const float* embed = (const float*)d_in[1];
    const float* pw    = (const float*)d_in[2];
    const float* pb    = (const float*)d_in[3];
    float* out = (float*)d_out;

    // ws layout (floats), ~59.1 MB:
    // resid 16MB | U 16MB (zh/zl; u aliases, s<=64) | ehi/elo 8MB |
    // Wt2 hi/lo 12MB (kp0-2 rows reused as Pl segs after si=6) |
    // esq 16KB | minbuf 64KB | bm2 4MB | Pl tail 3MB
    // Ph (fp16, 12.6MB) lives in d_out (out written only by k_final).
    float* resid = (float*)d_ws;
    float* Ubase = resid + 4194304;
    _Float16* zh = (_Float16*)Ubase;
    _Float16* zl = zh + 4194304;
    float* u = Ubase;
    _Float16* ehi = (_Float16*)(Ubase + 4194304);
    _Float16* elo = ehi + 2097152;
    _Float16* whi = elo + 2097152;
    _Float16* wlo = whi + 3145728;
    float* esq = (float*)(wlo + 3145728);
    unsigned long long* minbuf = (unsigned long long*)(esq + 4096);
    unsigned long long* bm2 = (unsigned long long*)(minbuf + 8192);
    _Float16* Ph = (_Float16*)d_out;
    _Float16* Pl0 = whi;                        // rows 0..1535   (dead kp0-2)
    _Float16* Pl1 = wlo;                        // rows 1536..3071 (dead kp0-2)
    _Float16* Pl2 = (_Float16*)(bm2 + 524288);  // rows 3072..4095 (3MB tail)

    k_prep_embed<<<1024, 256, 0, stream>>>(embed, ehi, elo, esq);
    k_split_w<<<12288, 256, 0, stream>>>(pw, whi, wlo);

    const int SCv[10] = {1, 2, 4, 8, 16, 32, 64, 128, 256, 512};
    // PHI_IDX with float64-ulp tie-breaks at si=2 and si=7 (verified round 2)
    const int PIv[10] = {0, 0, 1, 1, 1, 2, 2, 3, 3, 3};
    for (int si = 0; si < 10; ++si) {
        int s = SCv[si];
        int M = 16 * s;
        int kp = PIv[si];
        int lg = __builtin_ctz((unsigned)s);
        float scale = (float)s / 512.0f;
        const float* src = (si == 0) ? x : resid;
        if (s <= 8)
            k_zmean_s<<<16 * s * 8, 256, 0, stream>>>(src, zh, zl, s, lg);
        else
            k_zmean<<<(M * 512) / 256, 256, 0, stream>>>(src, zh, zl, s, lg);
        k_dist1<<<dim3((M + 127) / 128, 32), 256, 0, stream>>>(zh, ehi, esq, bm2, M);
        k_refine<<<(M + 3) / 4, 256, 0, stream>>>(zh, zl, embed, bm2, minbuf, M);
        if (si <= 6) {
            k_phi<<<dim3((M + 127) / 128, 12), 256, 0, stream>>>(ehi, elo,
                    whi + (size_t)kp * 1536 * 512, wlo + (size_t)kp * 1536 * 512, minbuf, u, M);
            k_combine<<<4096, 256, 0, stream>>>(u, embed, minbuf, pb + kp * 512, src, resid, s, scale);
        } else {
            if (si == 7)
                k_pmat<<<dim3(32, 12), 256, 0, stream>>>(ehi, elo,
                        whi + (size_t)3 * 1536 * 512, wlo + (size_t)3 * 1536 * 512,
                        Ph, Pl0, Pl1, Pl2);
            k_combineP<<<4096, 256, 0, stream>>>(Ph, Pl0, Pl1, Pl2, embed, minbuf,
                    pb + 3 * 512, src, resid, s, scale);
        }
    }
    k_final<<<4096, 256, 0, stream>>>(x, resid, out);
}